// Round 5
// baseline (1296.093 us; speedup 1.0000x reference)
//
#include <hip/hip_runtime.h>

// R5: single persistent mega-kernel. Hypothesis: with per-phase work modeling
// to only ~100us but wall=235us, the dominant unexplained term is dispatch
// boundary overhead (~7us x 9 dispatches, inferred from R0->R1: -44us for
// -3 dispatches -128MB). Collapse all phases into one kernel with manual
// device-wide barriers (all 768 blocks co-resident by construction).

#define EPS_BN 1e-5f
#define NEG_SLOPE 0.01f

#define BINSHIFT 9                 // 512 nodes per bin
#define NBINS_LDS 200
#define BUFCAP 22                  // 200*22*8 = 35.2KB LDS staging
#define GSTRIDE 16
#define NBLK 768                   // 3/CU needed; capacity>=4/CU by LDS+VGPR -> co-resident guaranteed
#define NTHR 256

// ---- bf16x2 pack/unpack (RNE) ----
__device__ __forceinline__ uint32_t pack2_bf16(float x, float y) {
    uint32_t ux = __float_as_uint(x);
    uint32_t uy = __float_as_uint(y);
    ux = (ux + 0x7fffu + ((ux >> 16) & 1u)) >> 16;
    uy = (uy + 0x7fffu + ((uy >> 16) & 1u)) >> 16;
    return (uy << 16) | (ux & 0xffffu);
}
__device__ __forceinline__ float bf_lo(uint32_t p) { return __uint_as_float(p << 16); }
__device__ __forceinline__ float bf_hi(uint32_t p) { return __uint_as_float(p & 0xffff0000u); }

// ---- per-phase LDS layouts, union'd (max = SStage 36.8KB; 4 blocks/CU) ----
struct SStage { int2 bbuf[NBINS_LDS][BUFCAP]; int bcnt[NBINS_LDS]; int gpos[NBINS_LDS]; };
struct SFill  { int lcnt[1 << BINSHIFT]; int loff[1 << BINSHIFT]; int ps[256]; };
struct SL1 { float sW1[192]; float sSc[64]; float sSh[64]; float sW2[4096]; float sH[32][64]; float sDinv[32]; };
struct SL2 { float sW3[2048]; float sSc[64]; float sSh[64]; float sH[32][64]; float sDinv[32]; };
struct SL3 { float sSc[32]; float sSh[32]; float sAcc[16][32]; int sCnt[16]; };
union SMem { SStage st; SFill fi; SL1 l1; SL2 l2; SL3 l3; };

// ---- device-wide barrier: sense-reversing generation barrier, agent scope.
// All NBLK blocks are co-resident (LDS 36.9KB -> 4/CU, VGPR<=128 via
// launch_bounds -> capacity 1024 >= 768), so spinning is deadlock-free.
// Agent-scope acquire/release emit the cross-XCD L2 writeback/invalidate
// (G16): phase outputs are visible across XCDs after the barrier.
__device__ __forceinline__ void gridbar(int* bar, int* gen) {
    __syncthreads();
    __threadfence();
    if (threadIdx.x == 0) {
        int g = __hip_atomic_load(gen, __ATOMIC_RELAXED, __HIP_MEMORY_SCOPE_AGENT);
        int t = __hip_atomic_fetch_add(bar, 1, __ATOMIC_ACQ_REL, __HIP_MEMORY_SCOPE_AGENT);
        if (t == NBLK - 1) {
            __hip_atomic_store(bar, 0, __ATOMIC_RELAXED, __HIP_MEMORY_SCOPE_AGENT);
            __hip_atomic_fetch_add(gen, 1, __ATOMIC_ACQ_REL, __HIP_MEMORY_SCOPE_AGENT);
        } else {
            while (__hip_atomic_load(gen, __ATOMIC_ACQUIRE, __HIP_MEMORY_SCOPE_AGENT) == g)
                __builtin_amdgcn_s_sleep(1);
        }
    }
    __syncthreads();
}

__global__ void __launch_bounds__(NTHR, 4) mega_kernel(
        const int* __restrict__ src, const int* __restrict__ dst,
        const float* __restrict__ x, const int* __restrict__ batch,
        const float* __restrict__ W1, const float* __restrict__ b1,
        const float* __restrict__ g1, const float* __restrict__ be1,
        const float* __restrict__ rm1, const float* __restrict__ rv1,
        const float* __restrict__ W2,
        const float* __restrict__ b2, const float* __restrict__ g2,
        const float* __restrict__ be2, const float* __restrict__ rm2,
        const float* __restrict__ rv2,
        const float* __restrict__ W3,
        const float* __restrict__ b3, const float* __restrict__ g3,
        const float* __restrict__ be3, const float* __restrict__ rm3,
        const float* __restrict__ rv3,
        int* gcur, int2* staged,                 // staged aliases Tp/Tp2: no restrict
        int* __restrict__ rowptr, int* __restrict__ cnt,
        float* __restrict__ dinv, float4* __restrict__ xs,
        int* __restrict__ eidx,
        uint32_t* Tp, uint32_t* Tp2,             // alias staged: no restrict
        float* __restrict__ gcnt, float* __restrict__ out,
        int N, int E, int G, int nbins, int cap, int chunk) {
    __shared__ SMem sm;
    int* bar = gcur + 3200;
    int* gen = gcur + 3201;
    const int tid = threadIdx.x;

    // ================= P1: zero out/gcnt + stage multisplit =================
    for (int i = blockIdx.x * NTHR + tid; i < G * 33; i += NBLK * NTHR) {
        if (i < G * 32) out[i] = 0.f; else gcnt[i - G * 32] = 0.f;
    }
    {
        SStage& S = sm.st;
        for (int i = tid; i < nbins; i += NTHR) S.bcnt[i] = 0;
        __syncthreads();
        int e0 = blockIdx.x * chunk;
        int e1 = min(e0 + chunk, E);
        for (int base = e0; base < e1; base += NTHR * 4) {
            int e = base + tid * 4;
            int s0, s1, s2, s3, d0, d1, d2, d3;
            int ne = 0;
            if (e + 4 <= e1) {
                int4 s4 = *(const int4*)(src + e);
                int4 d4 = *(const int4*)(dst + e);
                s0 = s4.x; s1 = s4.y; s2 = s4.z; s3 = s4.w;
                d0 = d4.x; d1 = d4.y; d2 = d4.z; d3 = d4.w;
                ne = 4;
            } else {
                int k = 0;
                for (; e + k < e1 && k < 4; ++k) {
                    int sv = src[e + k], dv = dst[e + k];
                    if (k == 0) { s0 = sv; d0 = dv; }
                    else if (k == 1) { s1 = sv; d1 = dv; }
                    else if (k == 2) { s2 = sv; d2 = dv; }
                    else { s3 = sv; d3 = dv; }
                }
                ne = k;
            }
            #pragma unroll
            for (int k = 0; k < 4; ++k) {
                if (k >= ne) break;
                int s = (k == 0) ? s0 : (k == 1) ? s1 : (k == 2) ? s2 : s3;
                int d = (k == 0) ? d0 : (k == 1) ? d1 : (k == 2) ? d2 : d3;
                int bin = d >> BINSHIFT;
                int pos = atomicAdd(&S.bcnt[bin], 1);
                if (pos < BUFCAP) {
                    S.bbuf[bin][pos] = make_int2(s, d);
                } else {
                    int gp = atomicAdd(&gcur[bin * GSTRIDE], 1);
                    staged[(size_t)bin * cap + gp] = make_int2(s, d);
                }
            }
        }
        __syncthreads();
        for (int b = tid; b < nbins; b += NTHR) {
            int c = min(S.bcnt[b], BUFCAP);
            S.gpos[b] = (c > 0) ? atomicAdd(&gcur[b * GSTRIDE], c) : 0;
        }
        __syncthreads();
        int grp = tid >> 4, lane16 = tid & 15;
        for (int b = grp; b < nbins; b += 16) {
            int c = min(S.bcnt[b], BUFCAP);
            int gp = S.gpos[b];
            for (int i = lane16; i < c; i += 16)
                staged[(size_t)b * cap + gp + i] = S.bbuf[b][i];
        }
    }
    gridbar(bar, gen);

    // ================= P2: per-bin CSR fill =================
    if (blockIdx.x < nbins) {
        SFill& S = sm.fi;
        int bin = blockIdx.x;
        int v = (tid < nbins && tid < bin) ? gcur[tid * GSTRIDE] : 0;
        S.ps[tid] = v;
        __syncthreads();
        for (int off = 128; off; off >>= 1) {
            if (tid < off) S.ps[tid] += S.ps[tid + off];
            __syncthreads();
        }
        int bb = S.ps[0];
        __syncthreads();
        int node0 = bin << BINSHIFT;
        int nn = min(1 << BINSHIFT, N - node0);
        int nrec = gcur[bin * GSTRIDE];
        const int2* recs = staged + (size_t)bin * cap;
        for (int i = tid; i < (1 << BINSHIFT); i += NTHR) S.lcnt[i] = 0;
        __syncthreads();
        for (int t = tid; t < nrec; t += NTHR) atomicAdd(&S.lcnt[recs[t].y - node0], 1);
        __syncthreads();
        int p0 = S.lcnt[2 * tid], p1 = S.lcnt[2 * tid + 1];
        int pv = p0 + p1;
        S.ps[tid] = pv;
        __syncthreads();
        for (int off = 1; off < 256; off <<= 1) {
            int t = (tid >= off) ? S.ps[tid - off] : 0;
            __syncthreads();
            S.ps[tid] += t;
            __syncthreads();
        }
        int base = S.ps[tid] - pv;
        S.loff[2 * tid] = base;
        S.loff[2 * tid + 1] = base + p0;
        __syncthreads();
        for (int i = tid; i < nn; i += NTHR) {
            int node = node0 + i;
            rowptr[node] = bb + S.loff[i];
            cnt[node] = S.lcnt[i];
            float di = rsqrtf((float)(S.lcnt[i] + 1));   // +1 self-loop
            dinv[node] = di;
            const float* xr = x + (size_t)node * 3;
            xs[node] = make_float4(xr[0] * di, xr[1] * di, xr[2] * di, 0.f);
            S.lcnt[i] = 0;                               // reuse as cursor
        }
        __syncthreads();
        for (int t = tid; t < nrec; t += NTHR) {
            int2 r = recs[t];
            int li = r.y - node0;
            int p = atomicAdd(&S.lcnt[li], 1);
            eidx[bb + S.loff[li] + p] = r.x;
        }
    }
    gridbar(bar, gen);

    // ================= P3: layer1 gather + 3->64 + BN + GEMM W2 + pack =================
    {
        SL1& S = sm.l1;
        for (int i = tid; i < 64 * 64; i += NTHR) S.sW2[i] = W2[i];
        if (tid < 192) S.sW1[tid] = W1[tid];
        if (tid < 64) {
            float sc = rsqrtf(rv1[tid] + EPS_BN) * g1[tid];
            S.sSc[tid] = sc;
            S.sSh[tid] = (b1[tid] - rm1[tid]) * sc + be1[tid];
        }
        __syncthreads();
        const int NV = (N + 31) / 32;
        int lane = tid & 7;
        int nl = tid >> 3;
        int fp = tid & 31;
        int ng = tid >> 5;
        for (int vb = blockIdx.x; vb < NV; vb += NBLK) {
            int node = vb * 32 + nl;
            int m = min(node, N - 1);
            int start = rowptr[m], deg = cnt[m];
            float ax = 0.f, ay = 0.f, az = 0.f;
            for (int j = lane; j < deg; j += 8) {
                float4 v = xs[eidx[start + j]];
                ax += v.x; ay += v.y; az += v.z;
            }
            #pragma unroll
            for (int o = 4; o; o >>= 1) {
                ax += __shfl_xor(ax, o, 8);
                ay += __shfl_xor(ay, o, 8);
                az += __shfl_xor(az, o, 8);
            }
            float4 self = xs[m];
            float di = dinv[m];
            float gx = (ax + self.x) * di, gy = (ay + self.y) * di, gz = (az + self.z) * di;
            if (lane == 0) S.sDinv[nl] = di;
            int f0 = lane * 8;
            #pragma unroll
            for (int hh = 0; hh < 2; ++hh) {
                float4 hv;
                #pragma unroll
                for (int q = 0; q < 4; ++q) {
                    int f = f0 + 4 * hh + q;
                    float a = gx * S.sW1[f] + gy * S.sW1[64 + f] + gz * S.sW1[128 + f];
                    float y = a * S.sSc[f] + S.sSh[f];
                    ((float*)&hv)[q] = (y >= 0.f) ? y : NEG_SLOPE * y;
                }
                *(float4*)&S.sH[nl][f0 + 4 * hh] = hv;
            }
            __syncthreads();
            const float2* w2 = (const float2*)S.sW2 + fp;
            const float4* sH0 = (const float4*)&S.sH[ng][0];
            const float4* sH1 = (const float4*)&S.sH[ng + 8][0];
            const float4* sH2 = (const float4*)&S.sH[ng + 16][0];
            const float4* sH3 = (const float4*)&S.sH[ng + 24][0];
            float a00 = 0.f, a01 = 0.f, a10 = 0.f, a11 = 0.f;
            float a20 = 0.f, a21 = 0.f, a30 = 0.f, a31 = 0.f;
            #pragma unroll 4
            for (int k4 = 0; k4 < 16; ++k4) {
                float4 h0 = sH0[k4];
                float4 h1 = sH1[k4];
                float4 h2 = sH2[k4];
                float4 h3 = sH3[k4];
                float2 w;
                w = w2[(4 * k4 + 0) * 32];
                a00 = fmaf(h0.x, w.x, a00); a01 = fmaf(h0.x, w.y, a01);
                a10 = fmaf(h1.x, w.x, a10); a11 = fmaf(h1.x, w.y, a11);
                a20 = fmaf(h2.x, w.x, a20); a21 = fmaf(h2.x, w.y, a21);
                a30 = fmaf(h3.x, w.x, a30); a31 = fmaf(h3.x, w.y, a31);
                w = w2[(4 * k4 + 1) * 32];
                a00 = fmaf(h0.y, w.x, a00); a01 = fmaf(h0.y, w.y, a01);
                a10 = fmaf(h1.y, w.x, a10); a11 = fmaf(h1.y, w.y, a11);
                a20 = fmaf(h2.y, w.x, a20); a21 = fmaf(h2.y, w.y, a21);
                a30 = fmaf(h3.y, w.x, a30); a31 = fmaf(h3.y, w.y, a31);
                w = w2[(4 * k4 + 2) * 32];
                a00 = fmaf(h0.z, w.x, a00); a01 = fmaf(h0.z, w.y, a01);
                a10 = fmaf(h1.z, w.x, a10); a11 = fmaf(h1.z, w.y, a11);
                a20 = fmaf(h2.z, w.x, a20); a21 = fmaf(h2.z, w.y, a21);
                a30 = fmaf(h3.z, w.x, a30); a31 = fmaf(h3.z, w.y, a31);
                w = w2[(4 * k4 + 3) * 32];
                a00 = fmaf(h0.w, w.x, a00); a01 = fmaf(h0.w, w.y, a01);
                a10 = fmaf(h1.w, w.x, a10); a11 = fmaf(h1.w, w.y, a11);
                a20 = fmaf(h2.w, w.x, a20); a21 = fmaf(h2.w, w.y, a21);
                a30 = fmaf(h3.w, w.x, a30); a31 = fmaf(h3.w, w.y, a31);
            }
            int nb = vb * 32;
            int n0 = nb + ng, n1 = nb + ng + 8, n2 = nb + ng + 16, n3 = nb + ng + 24;
            if (n0 < N) { float d = S.sDinv[ng];      Tp[(size_t)n0 * 32 + fp] = pack2_bf16(a00 * d, a01 * d); }
            if (n1 < N) { float d = S.sDinv[ng + 8];  Tp[(size_t)n1 * 32 + fp] = pack2_bf16(a10 * d, a11 * d); }
            if (n2 < N) { float d = S.sDinv[ng + 16]; Tp[(size_t)n2 * 32 + fp] = pack2_bf16(a20 * d, a21 * d); }
            if (n3 < N) { float d = S.sDinv[ng + 24]; Tp[(size_t)n3 * 32 + fp] = pack2_bf16(a30 * d, a31 * d); }
            __syncthreads();                             // sH reused next vb
        }
    }
    gridbar(bar, gen);

    // ================= P4: layer2 gather + BN + GEMM W3 + pack =================
    {
        SL2& S = sm.l2;
        for (int i = tid; i < 64 * 32; i += NTHR) S.sW3[i] = W3[i];
        if (tid < 64) {
            float sc = rsqrtf(rv2[tid] + EPS_BN) * g2[tid];
            S.sSc[tid] = sc;
            S.sSh[tid] = (b2[tid] - rm2[tid]) * sc + be2[tid];
        }
        __syncthreads();
        const int NV = (N + 31) / 32;
        int fq = tid & 7;
        int nl = tid >> 3;
        int fp = tid & 15;
        int ng = tid >> 4;
        for (int vb = blockIdx.x; vb < NV; vb += NBLK) {
            int node = vb * 32 + nl;
            int m = min(node, N - 1);
            const uint4* T4 = (const uint4*)Tp + fq;
            int start = rowptr[m];
            int deg = cnt[m];
            uint4 ts = T4[(size_t)m * 8];
            float a0 = bf_lo(ts.x), a1 = bf_hi(ts.x), a2 = bf_lo(ts.y), a3 = bf_hi(ts.y);
            float a4 = bf_lo(ts.z), a5 = bf_hi(ts.z), a6 = bf_lo(ts.w), a7 = bf_hi(ts.w);
            float c0 = 0.f, c1 = 0.f, c2 = 0.f, c3 = 0.f;
            float c4 = 0.f, c5 = 0.f, c6 = 0.f, c7 = 0.f;
            const int* ep = eidx + start;
            int j = 0;
            for (; j + 4 <= deg; j += 4) {
                int s0 = ep[j], s1 = ep[j + 1], s2 = ep[j + 2], s3 = ep[j + 3];
                uint4 t0 = T4[(size_t)s0 * 8];
                uint4 t1 = T4[(size_t)s1 * 8];
                uint4 t2 = T4[(size_t)s2 * 8];
                uint4 t3 = T4[(size_t)s3 * 8];
                a0 += bf_lo(t0.x) + bf_lo(t2.x);  a1 += bf_hi(t0.x) + bf_hi(t2.x);
                a2 += bf_lo(t0.y) + bf_lo(t2.y);  a3 += bf_hi(t0.y) + bf_hi(t2.y);
                a4 += bf_lo(t0.z) + bf_lo(t2.z);  a5 += bf_hi(t0.z) + bf_hi(t2.z);
                a6 += bf_lo(t0.w) + bf_lo(t2.w);  a7 += bf_hi(t0.w) + bf_hi(t2.w);
                c0 += bf_lo(t1.x) + bf_lo(t3.x);  c1 += bf_hi(t1.x) + bf_hi(t3.x);
                c2 += bf_lo(t1.y) + bf_lo(t3.y);  c3 += bf_hi(t1.y) + bf_hi(t3.y);
                c4 += bf_lo(t1.z) + bf_lo(t3.z);  c5 += bf_hi(t1.z) + bf_hi(t3.z);
                c6 += bf_lo(t1.w) + bf_lo(t3.w);  c7 += bf_hi(t1.w) + bf_hi(t3.w);
            }
            for (; j < deg; ++j) {
                uint4 t0 = T4[(size_t)ep[j] * 8];
                a0 += bf_lo(t0.x); a1 += bf_hi(t0.x);
                a2 += bf_lo(t0.y); a3 += bf_hi(t0.y);
                a4 += bf_lo(t0.z); a5 += bf_hi(t0.z);
                a6 += bf_lo(t0.w); a7 += bf_hi(t0.w);
            }
            float di = dinv[m];
            if (fq == 0) S.sDinv[nl] = di;
            int f0 = 8 * fq;
            float av[8] = {a0 + c0, a1 + c1, a2 + c2, a3 + c3,
                           a4 + c4, a5 + c5, a6 + c6, a7 + c7};
            #pragma unroll
            for (int hh = 0; hh < 2; ++hh) {
                float4 hv;
                #pragma unroll
                for (int q = 0; q < 4; ++q) {
                    int f = f0 + 4 * hh + q;
                    float y = av[4 * hh + q] * di * S.sSc[f] + S.sSh[f];
                    ((float*)&hv)[q] = (y >= 0.f) ? y : NEG_SLOPE * y;
                }
                *(float4*)&S.sH[nl][f0 + 4 * hh] = hv;
            }
            __syncthreads();
            const float2* w3 = (const float2*)S.sW3 + fp;
            const float4* sHA = (const float4*)&S.sH[ng][0];
            const float4* sHB = (const float4*)&S.sH[ng + 16][0];
            float p0 = 0.f, p1 = 0.f, q0 = 0.f, q1 = 0.f;
            #pragma unroll 4
            for (int k4 = 0; k4 < 16; ++k4) {
                float4 hA = sHA[k4];
                float4 hB = sHB[k4];
                float2 w;
                w = w3[(4 * k4 + 0) * 16];
                p0 = fmaf(hA.x, w.x, p0); p1 = fmaf(hA.x, w.y, p1);
                q0 = fmaf(hB.x, w.x, q0); q1 = fmaf(hB.x, w.y, q1);
                w = w3[(4 * k4 + 1) * 16];
                p0 = fmaf(hA.y, w.x, p0); p1 = fmaf(hA.y, w.y, p1);
                q0 = fmaf(hB.y, w.x, q0); q1 = fmaf(hB.y, w.y, q1);
                w = w3[(4 * k4 + 2) * 16];
                p0 = fmaf(hA.z, w.x, p0); p1 = fmaf(hA.z, w.y, p1);
                q0 = fmaf(hB.z, w.x, q0); q1 = fmaf(hB.z, w.y, q1);
                w = w3[(4 * k4 + 3) * 16];
                p0 = fmaf(hA.w, w.x, p0); p1 = fmaf(hA.w, w.y, p1);
                q0 = fmaf(hB.w, w.x, q0); q1 = fmaf(hB.w, w.y, q1);
            }
            int nb = vb * 32;
            int nA = nb + ng, nB = nb + ng + 16;
            if (nA < N) { float d = S.sDinv[ng];      Tp2[(size_t)nA * 16 + fp] = pack2_bf16(p0 * d, p1 * d); }
            if (nB < N) { float d = S.sDinv[ng + 16]; Tp2[(size_t)nB * 16 + fp] = pack2_bf16(q0 * d, q1 * d); }
            __syncthreads();                             // sH reused next vb
        }
    }
    gridbar(bar, gen);

    // ================= P5: layer3 gather + BN + mean-pool accumulate =================
    {
        SL3& S = sm.l3;
        if (tid < 32) {
            float sc = rsqrtf(rv3[tid] + EPS_BN) * g3[tid];
            S.sSc[tid] = sc;
            S.sSh[tid] = (b3[tid] - rm3[tid]) * sc + be3[tid];
        }
        const int NV = (N + 63) / 64;
        int fq = tid & 3;
        int nl = tid >> 2;
        for (int vb = blockIdx.x; vb < NV; vb += NBLK) {
            for (int i = tid; i < 16 * 32; i += NTHR) ((float*)S.sAcc)[i] = 0.f;
            if (tid < 16) S.sCnt[tid] = 0;
            __syncthreads();
            int node = vb * 64 + nl;
            bool valid = node < N;
            int m = valid ? node : N - 1;
            const uint4* T4 = (const uint4*)Tp2 + fq;
            int start = rowptr[m];
            int deg = cnt[m];
            uint4 ts = T4[(size_t)m * 4];
            float a0 = bf_lo(ts.x), a1 = bf_hi(ts.x), a2 = bf_lo(ts.y), a3 = bf_hi(ts.y);
            float a4 = bf_lo(ts.z), a5 = bf_hi(ts.z), a6 = bf_lo(ts.w), a7 = bf_hi(ts.w);
            float c0 = 0.f, c1 = 0.f, c2 = 0.f, c3 = 0.f;
            float c4 = 0.f, c5 = 0.f, c6 = 0.f, c7 = 0.f;
            const int* ep = eidx + start;
            int j = 0;
            for (; j + 4 <= deg; j += 4) {
                int s0 = ep[j], s1 = ep[j + 1], s2 = ep[j + 2], s3 = ep[j + 3];
                uint4 t0 = T4[(size_t)s0 * 4];
                uint4 t1 = T4[(size_t)s1 * 4];
                uint4 t2 = T4[(size_t)s2 * 4];
                uint4 t3 = T4[(size_t)s3 * 4];
                a0 += bf_lo(t0.x) + bf_lo(t2.x);  a1 += bf_hi(t0.x) + bf_hi(t2.x);
                a2 += bf_lo(t0.y) + bf_lo(t2.y);  a3 += bf_hi(t0.y) + bf_hi(t2.y);
                a4 += bf_lo(t0.z) + bf_lo(t2.z);  a5 += bf_hi(t0.z) + bf_hi(t2.z);
                a6 += bf_lo(t0.w) + bf_lo(t2.w);  a7 += bf_hi(t0.w) + bf_hi(t2.w);
                c0 += bf_lo(t1.x) + bf_lo(t3.x);  c1 += bf_hi(t1.x) + bf_hi(t3.x);
                c2 += bf_lo(t1.y) + bf_lo(t3.y);  c3 += bf_hi(t1.y) + bf_hi(t3.y);
                c4 += bf_lo(t1.z) + bf_lo(t3.z);  c5 += bf_hi(t1.z) + bf_hi(t3.z);
                c6 += bf_lo(t1.w) + bf_lo(t3.w);  c7 += bf_hi(t1.w) + bf_hi(t3.w);
            }
            for (; j < deg; ++j) {
                uint4 t0 = T4[(size_t)ep[j] * 4];
                a0 += bf_lo(t0.x); a1 += bf_hi(t0.x);
                a2 += bf_lo(t0.y); a3 += bf_hi(t0.y);
                a4 += bf_lo(t0.z); a5 += bf_hi(t0.z);
                a6 += bf_lo(t0.w); a7 += bf_hi(t0.w);
            }
            float di = dinv[m];
            int f0 = 8 * fq;
            float av[8] = {a0 + c0, a1 + c1, a2 + c2, a3 + c3,
                           a4 + c4, a5 + c5, a6 + c6, a7 + c7};
            float y[8];
            #pragma unroll
            for (int q = 0; q < 8; ++q) {
                float yy = av[q] * di * S.sSc[f0 + q] + S.sSh[f0 + q];
                y[q] = (yy >= 0.f) ? yy : NEG_SLOPE * yy;
            }
            int g0 = batch[vb * 64];
            if (valid) {
                int g = batch[node];
                int slot = g - g0;
                if (slot < 16) {
                    #pragma unroll
                    for (int q = 0; q < 8; ++q) atomicAdd(&S.sAcc[slot][f0 + q], y[q]);
                    if (fq == 0) atomicAdd(&S.sCnt[slot], 1);
                } else {
                    #pragma unroll
                    for (int q = 0; q < 8; ++q) atomicAdd(&out[(g << 5) + f0 + q], y[q]);
                    if (fq == 0) atomicAdd(&gcnt[g], 1.f);
                }
            }
            __syncthreads();
            for (int i = tid; i < 16 * 32; i += NTHR) {
                int s = i >> 5;
                if (S.sCnt[s] > 0)
                    atomicAdd(&out[((g0 + s) << 5) + (i & 31)], ((float*)S.sAcc)[i]);
            }
            if (tid < 16 && S.sCnt[tid] > 0)
                atomicAdd(&gcnt[g0 + tid], (float)S.sCnt[tid]);
            __syncthreads();                             // sAcc reused next vb
        }
    }
    gridbar(bar, gen);

    // ================= P6: pool divide =================
    for (int t = blockIdx.x * NTHR + tid; t < (G << 5); t += NBLK * NTHR)
        out[t] /= fmaxf(gcnt[t >> 5], 1.0f);
}

extern "C" void kernel_launch(void* const* d_in, const int* in_sizes, int n_in,
                              void* d_out, int out_size, void* d_ws, size_t ws_size,
                              hipStream_t stream) {
    const float* x   = (const float*)d_in[0];
    const float* W1  = (const float*)d_in[1];
    const float* b1  = (const float*)d_in[2];
    const float* g1  = (const float*)d_in[3];
    const float* be1 = (const float*)d_in[4];
    const float* rm1 = (const float*)d_in[5];
    const float* rv1 = (const float*)d_in[6];
    const float* W2  = (const float*)d_in[7];
    const float* b2  = (const float*)d_in[8];
    const float* g2  = (const float*)d_in[9];
    const float* be2 = (const float*)d_in[10];
    const float* rm2 = (const float*)d_in[11];
    const float* rv2 = (const float*)d_in[12];
    const float* W3  = (const float*)d_in[13];
    const float* b3  = (const float*)d_in[14];
    const float* g3  = (const float*)d_in[15];
    const float* be3 = (const float*)d_in[16];
    const float* rm3 = (const float*)d_in[17];
    const float* rv3 = (const float*)d_in[18];
    const int* ei    = (const int*)d_in[19];
    const int* batch = (const int*)d_in[20];

    const int N = in_sizes[0] / 3;
    const int E = in_sizes[19] / 2;
    const int G = out_size / 32;
    const int* src = ei;
    const int* dst = ei + E;

    const int nbins = (N + (1 << BINSHIFT) - 1) >> BINSHIFT;          // 196 for N=100k
    const int cap = (((E / nbins) * 3) / 2 + 15) & ~15;               // 1.5x mean
    const int chunk = (((E + NBLK - 1) / NBLK) + 3) & ~3;             // 4-aligned

    // workspace layout (staged aliases Tp/Tp2 head, dead before Tp written;
    // gcur[3200]=bar, gcur[3201]=gen for the device-wide barrier)
    int*      gcur    = (int*)d_ws;                       // 3264 ints
    int*      cnt     = gcur + 3264;                      // N
    float*    dinv    = (float*)(cnt + N);                // N
    int*      rowptr  = (int*)(dinv + N);                 // N
    int*      eidx    = rowptr + N;                       // E
    float4*   xs      = (float4*)(((uintptr_t)(eidx + E) + 15) & ~(uintptr_t)15);  // N
    uint32_t* Tp      = (uint32_t*)(xs + N);              // N*32 (layer-2 input, packed bf16)
    uint32_t* Tp2     = Tp + (size_t)N * 32;              // N*16 (layer-3 input, packed bf16)
    float*    gcnt    = (float*)(Tp2 + (size_t)N * 16);   // G
    int2*     staged  = (int2*)Tp;                        // alias: dead before Tp written
    float*    out     = (float*)d_out;

    hipMemsetAsync(gcur, 0, 3264 * 4, stream);            // gcur + bar/gen
    mega_kernel<<<NBLK, NTHR, 0, stream>>>(
        src, dst, x, batch,
        W1, b1, g1, be1, rm1, rv1, W2,
        b2, g2, be2, rm2, rv2, W3,
        b3, g3, be3, rm3, rv3,
        gcur, staged, rowptr, cnt, dinv, xs, eidx,
        Tp, Tp2, gcnt, out,
        N, E, G, nbins, cap, chunk);
}

// Round 6
// 350.099 us; speedup vs baseline: 3.7021x; 3.7021x over previous
//
#include <hip/hip_runtime.h>

#define EPS_BN 1e-5f
#define NEG_SLOPE 0.01f

#define BINSHIFT 9                 // 512 nodes per bin (BINSHIFT 7 regressed: R3)
#define BINSIZE (1 << BINSHIFT)
#define NBINS_LDS 200              // supports N up to 102400
#define BUFCAP 24                  // LDS records per (block,bin)
#define GSTRIDE 16                 // gcur padding: one counter per 64B line

// ---- bf16x2 pack/unpack (RNE) ----
__device__ __forceinline__ uint32_t pack2_bf16(float x, float y) {
    uint32_t ux = __float_as_uint(x);
    uint32_t uy = __float_as_uint(y);
    ux = (ux + 0x7fffu + ((ux >> 16) & 1u)) >> 16;
    uy = (uy + 0x7fffu + ((uy >> 16) & 1u)) >> 16;
    return (uy << 16) | (ux & 0xffffu);
}
__device__ __forceinline__ float bf_lo(uint32_t p) { return __uint_as_float(p << 16); }
__device__ __forceinline__ float bf_hi(uint32_t p) { return __uint_as_float(p & 0xffff0000u); }

// ---- phase A: LDS multisplit; 4 edges/thread/iter; packed 4-B records.
// rec = (src << BINSHIFT) | (dst & (BINSIZE-1)); src < 2^17 so 26 bits total.
// R6: 4B records halve staged traffic AND stage LDS (40->21KB: 4->7 blk/CU).
__global__ void __launch_bounds__(256) stage_ms_kernel(
        const int* __restrict__ src, const int* __restrict__ dst,
        int* __restrict__ gcur, uint32_t* __restrict__ staged,
        int cap, int nbins, int E, int chunk) {
    __shared__ uint32_t bbuf[NBINS_LDS][BUFCAP];
    __shared__ int bcnt[NBINS_LDS];
    __shared__ int gpos[NBINS_LDS];
    for (int i = threadIdx.x; i < nbins; i += 256) bcnt[i] = 0;
    __syncthreads();
    int e0 = blockIdx.x * chunk;
    int e1 = min(e0 + chunk, E);
    for (int base = e0; base < e1; base += 1024) {       // 256 threads x 4 edges
        int e = base + threadIdx.x * 4;
        int s0, s1, s2, s3, d0, d1, d2, d3;
        int ne = 0;
        if (e + 4 <= e1) {
            int4 s4 = *(const int4*)(src + e);
            int4 d4 = *(const int4*)(dst + e);
            s0 = s4.x; s1 = s4.y; s2 = s4.z; s3 = s4.w;
            d0 = d4.x; d1 = d4.y; d2 = d4.z; d3 = d4.w;
            ne = 4;
        } else {
            int k = 0;
            for (; e + k < e1 && k < 4; ++k) {
                int sv = src[e + k], dv = dst[e + k];
                if (k == 0) { s0 = sv; d0 = dv; }
                else if (k == 1) { s1 = sv; d1 = dv; }
                else if (k == 2) { s2 = sv; d2 = dv; }
                else { s3 = sv; d3 = dv; }
            }
            ne = k;
        }
        #pragma unroll
        for (int k = 0; k < 4; ++k) {
            if (k >= ne) break;
            int s = (k == 0) ? s0 : (k == 1) ? s1 : (k == 2) ? s2 : s3;
            int d = (k == 0) ? d0 : (k == 1) ? d1 : (k == 2) ? d2 : d3;
            int bin = d >> BINSHIFT;
            uint32_t rec = ((uint32_t)s << BINSHIFT) | (uint32_t)(d & (BINSIZE - 1));
            int pos = atomicAdd(&bcnt[bin], 1);
            if (pos < BUFCAP) {
                bbuf[bin][pos] = rec;
            } else {                                     // rare: direct global append
                int gp = atomicAdd(&gcur[bin * GSTRIDE], 1);
                staged[(size_t)bin * cap + gp] = rec;
            }
        }
    }
    __syncthreads();
    // drain phase 1: one bin per THREAD -> all global atomics issue concurrently
    for (int b = threadIdx.x; b < nbins; b += 256) {
        int c = min(bcnt[b], BUFCAP);
        gpos[b] = (c > 0) ? atomicAdd(&gcur[b * GSTRIDE], c) : 0;
    }
    __syncthreads();
    // drain phase 2: cooperative 16-lane copy per bin
    int grp = threadIdx.x >> 4, lane = threadIdx.x & 15;
    for (int b = grp; b < nbins; b += 16) {
        int c = min(bcnt[b], BUFCAP);
        int gp = gpos[b];
        for (int i = lane; i < c; i += 16)
            staged[(size_t)b * cap + gp + i] = bbuf[b][i];
    }
}

// ---- phase B: per-bin CSR fill + rowptr/cnt/dinv/xs (R1 body, packed recs).
// Block 0 also zeroes out/gcnt.
__global__ void __launch_bounds__(256) fill_csr_kernel(
        const uint32_t* __restrict__ staged, const int* __restrict__ gcur,
        const float* __restrict__ x, int cap, int nbins,
        int* __restrict__ rowptr, int* __restrict__ cnt,
        float* __restrict__ dinv, float4* __restrict__ xs,
        int* __restrict__ eidx, int N,
        float* __restrict__ out, float* __restrict__ gcnt, int G) {
    __shared__ int lcnt[BINSIZE];
    __shared__ int loff[BINSIZE];
    __shared__ int ps[256];
    int bin = blockIdx.x;
    // ---- binbase = sum of gcur[i] for i < bin ----
    int v = (threadIdx.x < nbins && threadIdx.x < bin) ? gcur[threadIdx.x * GSTRIDE] : 0;
    ps[threadIdx.x] = v;
    __syncthreads();
    for (int off = 128; off; off >>= 1) {
        if (threadIdx.x < off) ps[threadIdx.x] += ps[threadIdx.x + off];
        __syncthreads();
    }
    int bb = ps[0];
    __syncthreads();
    // ---- block 0: zero pool accumulators ----
    if (bin == 0) {
        for (int i = threadIdx.x; i < G * 32; i += 256) out[i] = 0.f;
        for (int i = threadIdx.x; i < G; i += 256) gcnt[i] = 0.f;
    }
    int node0 = bin << BINSHIFT;
    int nn = min(BINSIZE, N - node0);
    int nrec = gcur[bin * GSTRIDE];
    const uint32_t* recs = staged + (size_t)bin * cap;
    for (int i = threadIdx.x; i < BINSIZE; i += 256) lcnt[i] = 0;
    __syncthreads();
    for (int t = threadIdx.x; t < nrec; t += 256)
        atomicAdd(&lcnt[recs[t] & (BINSIZE - 1)], 1);
    __syncthreads();
    int p0 = lcnt[2 * threadIdx.x], p1 = lcnt[2 * threadIdx.x + 1];
    int pv = p0 + p1;
    ps[threadIdx.x] = pv;
    __syncthreads();
    for (int off = 1; off < 256; off <<= 1) {
        int t = (threadIdx.x >= off) ? ps[threadIdx.x - off] : 0;
        __syncthreads();
        ps[threadIdx.x] += t;
        __syncthreads();
    }
    int base = ps[threadIdx.x] - pv;
    loff[2 * threadIdx.x] = base;
    loff[2 * threadIdx.x + 1] = base + p0;
    __syncthreads();
    for (int i = threadIdx.x; i < nn; i += 256) {
        int node = node0 + i;
        rowptr[node] = bb + loff[i];
        cnt[node] = lcnt[i];
        float di = rsqrtf((float)(lcnt[i] + 1));         // +1 self-loop
        dinv[node] = di;
        const float* xr = x + (size_t)node * 3;
        xs[node] = make_float4(xr[0] * di, xr[1] * di, xr[2] * di, 0.f);
        lcnt[i] = 0;                                     // reuse as cursor
    }
    __syncthreads();
    for (int t = threadIdx.x; t < nrec; t += 256) {
        uint32_t r = recs[t];
        int li = r & (BINSIZE - 1);
        int p = atomicAdd(&lcnt[li], 1);
        eidx[bb + loff[li] + p] = (int)(r >> BINSHIFT);  // block-private range
    }
}

// ---- fused layer1 + GEMM(64->64) + dinv-scale + bf16 pack (R4 body) ----
__global__ void __launch_bounds__(256) layer1_gemm2_kernel(
        const float4* __restrict__ xs, const int* __restrict__ rowptr,
        const int* __restrict__ cnt, const int* __restrict__ eidx,
        const float* __restrict__ dinv, const float* __restrict__ W1,
        const float* __restrict__ b1, const float* __restrict__ g1,
        const float* __restrict__ be1, const float* __restrict__ rm1,
        const float* __restrict__ rv1, const float* __restrict__ W2,
        uint32_t* __restrict__ Tp, int N) {
    __shared__ float sW1[3 * 64];
    __shared__ float sSc[64], sSh[64];
    __shared__ float sW2[64 * 64];
    __shared__ float sH[32][64];
    __shared__ float sDinv[32];
    for (int i = threadIdx.x; i < 64 * 64; i += 256) sW2[i] = W2[i];
    if (threadIdx.x < 192) sW1[threadIdx.x] = W1[threadIdx.x];
    if (threadIdx.x < 64) {
        int f = threadIdx.x;
        float sc = rsqrtf(rv1[f] + EPS_BN) * g1[f];
        sSc[f] = sc;
        sSh[f] = (b1[f] - rm1[f]) * sc + be1[f];
    }
    __syncthreads();
    int lane = threadIdx.x & 7;
    int nl = threadIdx.x >> 3;                           // 0..31
    int node = blockIdx.x * 32 + nl;
    int m = min(node, N - 1);                            // clamp; no early return (sync below)
    int start = rowptr[m], deg = cnt[m];
    float ax = 0.f, ay = 0.f, az = 0.f;
    for (int j = lane; j < deg; j += 8) {
        float4 v = xs[eidx[start + j]];
        ax += v.x; ay += v.y; az += v.z;
    }
    #pragma unroll
    for (int o = 4; o; o >>= 1) {
        ax += __shfl_xor(ax, o, 8);
        ay += __shfl_xor(ay, o, 8);
        az += __shfl_xor(az, o, 8);
    }
    float4 self = xs[m];
    float di = dinv[m];
    float gx = (ax + self.x) * di, gy = (ay + self.y) * di, gz = (az + self.z) * di;
    if (lane == 0) sDinv[nl] = di;
    int f0 = lane * 8;
    #pragma unroll
    for (int hh = 0; hh < 2; ++hh) {
        float4 hv;
        #pragma unroll
        for (int q = 0; q < 4; ++q) {
            int f = f0 + 4 * hh + q;
            float a = gx * sW1[f] + gy * sW1[64 + f] + gz * sW1[128 + f];
            float y = a * sSc[f] + sSh[f];
            ((float*)&hv)[q] = (y >= 0.f) ? y : NEG_SLOPE * y;
        }
        *(float4*)&sH[nl][f0 + 4 * hh] = hv;
    }
    __syncthreads();
    int fp = threadIdx.x & 31;                           // feature pair 0..31
    int ng = threadIdx.x >> 5;                           // 0..7
    const float2* w2 = (const float2*)sW2 + fp;          // float2 stride 32 per k
    const float4* sH0 = (const float4*)&sH[ng][0];
    const float4* sH1 = (const float4*)&sH[ng + 8][0];
    const float4* sH2 = (const float4*)&sH[ng + 16][0];
    const float4* sH3 = (const float4*)&sH[ng + 24][0];
    float a00 = 0.f, a01 = 0.f, a10 = 0.f, a11 = 0.f;
    float a20 = 0.f, a21 = 0.f, a30 = 0.f, a31 = 0.f;
    #pragma unroll 4
    for (int k4 = 0; k4 < 16; ++k4) {
        float4 h0 = sH0[k4];
        float4 h1 = sH1[k4];
        float4 h2 = sH2[k4];
        float4 h3 = sH3[k4];
        float2 w;
        w = w2[(4 * k4 + 0) * 32];
        a00 = fmaf(h0.x, w.x, a00); a01 = fmaf(h0.x, w.y, a01);
        a10 = fmaf(h1.x, w.x, a10); a11 = fmaf(h1.x, w.y, a11);
        a20 = fmaf(h2.x, w.x, a20); a21 = fmaf(h2.x, w.y, a21);
        a30 = fmaf(h3.x, w.x, a30); a31 = fmaf(h3.x, w.y, a31);
        w = w2[(4 * k4 + 1) * 32];
        a00 = fmaf(h0.y, w.x, a00); a01 = fmaf(h0.y, w.y, a01);
        a10 = fmaf(h1.y, w.x, a10); a11 = fmaf(h1.y, w.y, a11);
        a20 = fmaf(h2.y, w.x, a20); a21 = fmaf(h2.y, w.y, a21);
        a30 = fmaf(h3.y, w.x, a30); a31 = fmaf(h3.y, w.y, a31);
        w = w2[(4 * k4 + 2) * 32];
        a00 = fmaf(h0.z, w.x, a00); a01 = fmaf(h0.z, w.y, a01);
        a10 = fmaf(h1.z, w.x, a10); a11 = fmaf(h1.z, w.y, a11);
        a20 = fmaf(h2.z, w.x, a20); a21 = fmaf(h2.z, w.y, a21);
        a30 = fmaf(h3.z, w.x, a30); a31 = fmaf(h3.z, w.y, a31);
        w = w2[(4 * k4 + 3) * 32];
        a00 = fmaf(h0.w, w.x, a00); a01 = fmaf(h0.w, w.y, a01);
        a10 = fmaf(h1.w, w.x, a10); a11 = fmaf(h1.w, w.y, a11);
        a20 = fmaf(h2.w, w.x, a20); a21 = fmaf(h2.w, w.y, a21);
        a30 = fmaf(h3.w, w.x, a30); a31 = fmaf(h3.w, w.y, a31);
    }
    int base = blockIdx.x * 32;
    int n0 = base + ng, n1 = base + ng + 8, n2 = base + ng + 16, n3 = base + ng + 24;
    if (n0 < N) { float d = sDinv[ng];      Tp[(size_t)n0 * 32 + fp] = pack2_bf16(a00 * d, a01 * d); }
    if (n1 < N) { float d = sDinv[ng + 8];  Tp[(size_t)n1 * 32 + fp] = pack2_bf16(a10 * d, a11 * d); }
    if (n2 < N) { float d = sDinv[ng + 16]; Tp[(size_t)n2 * 32 + fp] = pack2_bf16(a20 * d, a21 * d); }
    if (n3 < N) { float d = sDinv[ng + 24]; Tp[(size_t)n3 * 32 + fp] = pack2_bf16(a30 * d, a31 * d); }
}

// ---- fused layer-2 gather + BN2 + LReLU + GEMM(64->32) + dinv-scale + pack ----
__global__ void __launch_bounds__(256) layer2_gather_gemm3_kernel(
        const uint32_t* __restrict__ Tp, const int* __restrict__ rowptr,
        const int* __restrict__ cnt, const int* __restrict__ eidx,
        const float* __restrict__ dinv,
        const float* __restrict__ b2, const float* __restrict__ g2,
        const float* __restrict__ be2, const float* __restrict__ rm2,
        const float* __restrict__ rv2, const float* __restrict__ W3,
        uint32_t* __restrict__ Tp2, int N) {
    __shared__ float sW3[64 * 32];
    __shared__ float sSc[64], sSh[64];
    __shared__ float sH[32][64];
    __shared__ float sDinv[32];
    for (int i = threadIdx.x; i < 64 * 32; i += 256) sW3[i] = W3[i];
    if (threadIdx.x < 64) {
        int f = threadIdx.x;
        float sc = rsqrtf(rv2[f] + EPS_BN) * g2[f];
        sSc[f] = sc;
        sSh[f] = (b2[f] - rm2[f]) * sc + be2[f];
    }
    __syncthreads();
    int fq = threadIdx.x & 7;
    int nl = threadIdx.x >> 3;                           // 0..31
    int node = blockIdx.x * 32 + nl;
    int m = min(node, N - 1);
    const uint4* T4 = (const uint4*)Tp + fq;             // stride 8 uint4 per node
    int start = rowptr[m];
    int deg = cnt[m];
    uint4 ts = T4[(size_t)m * 8];
    float a0 = bf_lo(ts.x), a1 = bf_hi(ts.x), a2 = bf_lo(ts.y), a3 = bf_hi(ts.y);
    float a4 = bf_lo(ts.z), a5 = bf_hi(ts.z), a6 = bf_lo(ts.w), a7 = bf_hi(ts.w);
    float c0 = 0.f, c1 = 0.f, c2 = 0.f, c3 = 0.f;
    float c4 = 0.f, c5 = 0.f, c6 = 0.f, c7 = 0.f;
    const int* ep = eidx + start;
    int j = 0;
    for (; j + 4 <= deg; j += 4) {
        int s0 = ep[j], s1 = ep[j + 1], s2 = ep[j + 2], s3 = ep[j + 3];
        uint4 t0 = T4[(size_t)s0 * 8];
        uint4 t1 = T4[(size_t)s1 * 8];
        uint4 t2 = T4[(size_t)s2 * 8];
        uint4 t3 = T4[(size_t)s3 * 8];
        a0 += bf_lo(t0.x) + bf_lo(t2.x);  a1 += bf_hi(t0.x) + bf_hi(t2.x);
        a2 += bf_lo(t0.y) + bf_lo(t2.y);  a3 += bf_hi(t0.y) + bf_hi(t2.y);
        a4 += bf_lo(t0.z) + bf_lo(t2.z);  a5 += bf_hi(t0.z) + bf_hi(t2.z);
        a6 += bf_lo(t0.w) + bf_lo(t2.w);  a7 += bf_hi(t0.w) + bf_hi(t2.w);
        c0 += bf_lo(t1.x) + bf_lo(t3.x);  c1 += bf_hi(t1.x) + bf_hi(t3.x);
        c2 += bf_lo(t1.y) + bf_lo(t3.y);  c3 += bf_hi(t1.y) + bf_hi(t3.y);
        c4 += bf_lo(t1.z) + bf_lo(t3.z);  c5 += bf_hi(t1.z) + bf_hi(t3.z);
        c6 += bf_lo(t1.w) + bf_lo(t3.w);  c7 += bf_hi(t1.w) + bf_hi(t3.w);
    }
    for (; j < deg; ++j) {
        uint4 t0 = T4[(size_t)ep[j] * 8];
        a0 += bf_lo(t0.x); a1 += bf_hi(t0.x);
        a2 += bf_lo(t0.y); a3 += bf_hi(t0.y);
        a4 += bf_lo(t0.z); a5 += bf_hi(t0.z);
        a6 += bf_lo(t0.w); a7 += bf_hi(t0.w);
    }
    float di = dinv[m];
    if (fq == 0) sDinv[nl] = di;
    int f0 = 8 * fq;
    float av[8] = {a0 + c0, a1 + c1, a2 + c2, a3 + c3,
                   a4 + c4, a5 + c5, a6 + c6, a7 + c7};
    #pragma unroll
    for (int hh = 0; hh < 2; ++hh) {
        float4 hv;
        #pragma unroll
        for (int q = 0; q < 4; ++q) {
            int f = f0 + 4 * hh + q;
            float y = av[4 * hh + q] * di * sSc[f] + sSh[f];
            ((float*)&hv)[q] = (y >= 0.f) ? y : NEG_SLOPE * y;
        }
        *(float4*)&sH[nl][f0 + 4 * hh] = hv;
    }
    __syncthreads();
    int fp = threadIdx.x & 15;                           // feature pair 0..15
    int ng = threadIdx.x >> 4;                           // 0..15
    const float2* w3 = (const float2*)sW3 + fp;          // float2 stride 16 per k
    const float4* sHA = (const float4*)&sH[ng][0];
    const float4* sHB = (const float4*)&sH[ng + 16][0];
    float p0 = 0.f, p1 = 0.f, q0 = 0.f, q1 = 0.f;
    #pragma unroll 4
    for (int k4 = 0; k4 < 16; ++k4) {
        float4 hA = sHA[k4];
        float4 hB = sHB[k4];
        float2 w;
        w = w3[(4 * k4 + 0) * 16];
        p0 = fmaf(hA.x, w.x, p0); p1 = fmaf(hA.x, w.y, p1);
        q0 = fmaf(hB.x, w.x, q0); q1 = fmaf(hB.x, w.y, q1);
        w = w3[(4 * k4 + 1) * 16];
        p0 = fmaf(hA.y, w.x, p0); p1 = fmaf(hA.y, w.y, p1);
        q0 = fmaf(hB.y, w.x, q0); q1 = fmaf(hB.y, w.y, q1);
        w = w3[(4 * k4 + 2) * 16];
        p0 = fmaf(hA.z, w.x, p0); p1 = fmaf(hA.z, w.y, p1);
        q0 = fmaf(hB.z, w.x, q0); q1 = fmaf(hB.z, w.y, q1);
        w = w3[(4 * k4 + 3) * 16];
        p0 = fmaf(hA.w, w.x, p0); p1 = fmaf(hA.w, w.y, p1);
        q0 = fmaf(hB.w, w.x, q0); q1 = fmaf(hB.w, w.y, q1);
    }
    int base = blockIdx.x * 32;
    int nA = base + ng, nB = base + ng + 16;
    if (nA < N) { float d = sDinv[ng];      Tp2[(size_t)nA * 16 + fp] = pack2_bf16(p0 * d, p1 * d); }
    if (nB < N) { float d = sDinv[ng + 16]; Tp2[(size_t)nB * 16 + fp] = pack2_bf16(q0 * d, q1 * d); }
}

// ---- fused layer-3 gather + BN3 + LReLU + mean-pool + last-block divide.
// R6: the final arriving block performs the mean-divide (saves pool_div
// dispatch). No spinning: only one block proceeds past the ticket.
#define SLOTS 16
__global__ void __launch_bounds__(256) layer3_gather_pool_kernel(
        const uint32_t* __restrict__ Tp2, const int* __restrict__ rowptr,
        const int* __restrict__ cnt, const int* __restrict__ eidx,
        const float* __restrict__ dinv, const int* __restrict__ batch,
        const float* __restrict__ b3, const float* __restrict__ g3,
        const float* __restrict__ be3, const float* __restrict__ rm3,
        const float* __restrict__ rv3,
        float* __restrict__ out, float* __restrict__ gcnt,
        int* __restrict__ done, int N, int G) {
    __shared__ float sSc[32], sSh[32];
    __shared__ float sAcc[SLOTS][32];
    __shared__ int sCnt[SLOTS];
    __shared__ int sLast;
    if (threadIdx.x < 32) {
        int f = threadIdx.x;
        float sc = rsqrtf(rv3[f] + EPS_BN) * g3[f];
        sSc[f] = sc;
        sSh[f] = (b3[f] - rm3[f]) * sc + be3[f];
    }
    for (int i = threadIdx.x; i < SLOTS * 32; i += 256) ((float*)sAcc)[i] = 0.f;
    if (threadIdx.x < SLOTS) sCnt[threadIdx.x] = 0;
    __syncthreads();
    int fq = threadIdx.x & 3;
    int nl = threadIdx.x >> 2;                           // 0..63
    int node = blockIdx.x * 64 + nl;
    bool valid = node < N;
    int m = valid ? node : N - 1;
    const uint4* T4 = (const uint4*)Tp2 + fq;            // stride 4 uint4 per node
    int start = rowptr[m];
    int deg = cnt[m];
    uint4 ts = T4[(size_t)m * 4];
    float a0 = bf_lo(ts.x), a1 = bf_hi(ts.x), a2 = bf_lo(ts.y), a3 = bf_hi(ts.y);
    float a4 = bf_lo(ts.z), a5 = bf_hi(ts.z), a6 = bf_lo(ts.w), a7 = bf_hi(ts.w);
    float c0 = 0.f, c1 = 0.f, c2 = 0.f, c3 = 0.f;
    float c4 = 0.f, c5 = 0.f, c6 = 0.f, c7 = 0.f;
    const int* ep = eidx + start;
    int j = 0;
    for (; j + 4 <= deg; j += 4) {
        int s0 = ep[j], s1 = ep[j + 1], s2 = ep[j + 2], s3 = ep[j + 3];
        uint4 t0 = T4[(size_t)s0 * 4];
        uint4 t1 = T4[(size_t)s1 * 4];
        uint4 t2 = T4[(size_t)s2 * 4];
        uint4 t3 = T4[(size_t)s3 * 4];
        a0 += bf_lo(t0.x) + bf_lo(t2.x);  a1 += bf_hi(t0.x) + bf_hi(t2.x);
        a2 += bf_lo(t0.y) + bf_lo(t2.y);  a3 += bf_hi(t0.y) + bf_hi(t2.y);
        a4 += bf_lo(t0.z) + bf_lo(t2.z);  a5 += bf_hi(t0.z) + bf_hi(t2.z);
        a6 += bf_lo(t0.w) + bf_lo(t2.w);  a7 += bf_hi(t0.w) + bf_hi(t2.w);
        c0 += bf_lo(t1.x) + bf_lo(t3.x);  c1 += bf_hi(t1.x) + bf_hi(t3.x);
        c2 += bf_lo(t1.y) + bf_lo(t3.y);  c3 += bf_hi(t1.y) + bf_hi(t3.y);
        c4 += bf_lo(t1.z) + bf_lo(t3.z);  c5 += bf_hi(t1.z) + bf_hi(t3.z);
        c6 += bf_lo(t1.w) + bf_lo(t3.w);  c7 += bf_hi(t1.w) + bf_hi(t3.w);
    }
    for (; j < deg; ++j) {
        uint4 t0 = T4[(size_t)ep[j] * 4];
        a0 += bf_lo(t0.x); a1 += bf_hi(t0.x);
        a2 += bf_lo(t0.y); a3 += bf_hi(t0.y);
        a4 += bf_lo(t0.z); a5 += bf_hi(t0.z);
        a6 += bf_lo(t0.w); a7 += bf_hi(t0.w);
    }
    float di = dinv[m];
    int f0 = 8 * fq;
    float av[8] = {a0 + c0, a1 + c1, a2 + c2, a3 + c3,
                   a4 + c4, a5 + c5, a6 + c6, a7 + c7};
    float y[8];
    #pragma unroll
    for (int q = 0; q < 8; ++q) {
        float yy = av[q] * di * sSc[f0 + q] + sSh[f0 + q];
        y[q] = (yy >= 0.f) ? yy : NEG_SLOPE * yy;
    }
    int g0 = batch[blockIdx.x * 64];                     // first node of block, always < N
    if (valid) {
        int g = batch[node];
        int slot = g - g0;
        if (slot < SLOTS) {
            #pragma unroll
            for (int q = 0; q < 8; ++q) atomicAdd(&sAcc[slot][f0 + q], y[q]);
            if (fq == 0) atomicAdd(&sCnt[slot], 1);
        } else {                                         // rare: block spans many graphs
            #pragma unroll
            for (int q = 0; q < 8; ++q) atomicAdd(&out[(g << 5) + f0 + q], y[q]);
            if (fq == 0) atomicAdd(&gcnt[g], 1.f);
        }
    }
    __syncthreads();
    for (int i = threadIdx.x; i < SLOTS * 32; i += 256) {
        int s = i >> 5;
        if (sCnt[s] > 0)
            atomicAdd(&out[((g0 + s) << 5) + (i & 31)], ((float*)sAcc)[i]);
    }
    if (threadIdx.x < SLOTS && sCnt[threadIdx.x] > 0)
        atomicAdd(&gcnt[g0 + threadIdx.x], (float)sCnt[threadIdx.x]);
    // ---- last-block-done: final block divides out by gcnt ----
    __threadfence();
    __syncthreads();
    if (threadIdx.x == 0) {
        int t = __hip_atomic_fetch_add(done, 1, __ATOMIC_ACQ_REL, __HIP_MEMORY_SCOPE_AGENT);
        sLast = (t == (int)gridDim.x - 1) ? 1 : 0;
    }
    __syncthreads();
    if (sLast) {
        for (int t = threadIdx.x; t < (G << 5); t += 256) {
            float o = __hip_atomic_load(&out[t], __ATOMIC_RELAXED, __HIP_MEMORY_SCOPE_AGENT);
            float c = __hip_atomic_load(&gcnt[t >> 5], __ATOMIC_RELAXED, __HIP_MEMORY_SCOPE_AGENT);
            out[t] = o / fmaxf(c, 1.0f);
        }
    }
}

extern "C" void kernel_launch(void* const* d_in, const int* in_sizes, int n_in,
                              void* d_out, int out_size, void* d_ws, size_t ws_size,
                              hipStream_t stream) {
    const float* x   = (const float*)d_in[0];
    const float* W1  = (const float*)d_in[1];
    const float* b1  = (const float*)d_in[2];
    const float* g1  = (const float*)d_in[3];
    const float* be1 = (const float*)d_in[4];
    const float* rm1 = (const float*)d_in[5];
    const float* rv1 = (const float*)d_in[6];
    const float* W2  = (const float*)d_in[7];
    const float* b2  = (const float*)d_in[8];
    const float* g2  = (const float*)d_in[9];
    const float* be2 = (const float*)d_in[10];
    const float* rm2 = (const float*)d_in[11];
    const float* rv2 = (const float*)d_in[12];
    const float* W3  = (const float*)d_in[13];
    const float* b3  = (const float*)d_in[14];
    const float* g3  = (const float*)d_in[15];
    const float* be3 = (const float*)d_in[16];
    const float* rm3 = (const float*)d_in[17];
    const float* rv3 = (const float*)d_in[18];
    const int* ei    = (const int*)d_in[19];
    const int* batch = (const int*)d_in[20];

    const int N = in_sizes[0] / 3;
    const int E = in_sizes[19] / 2;
    const int G = out_size / 32;
    const int* src = ei;
    const int* dst = ei + E;

    const int nbins = (N + BINSIZE - 1) >> BINSHIFT;                  // 196 for N=100k
    const int cap = (((E / nbins) * 3) / 2 + 15) & ~15;               // 1.5x mean
    const int STAGE_BLOCKS = 512;
    const int chunk = (((E + STAGE_BLOCKS - 1) / STAGE_BLOCKS) + 3) & ~3;  // 4-aligned

    // workspace layout (staged aliases Tp, dead before layer1_gemm2 writes Tp;
    // done-counter at gcur[256*GSTRIDE], covered by the memset)
    int*      gcur    = (int*)d_ws;                       // 256*GSTRIDE + 16
    int*      done    = gcur + 256 * GSTRIDE;             // 1 (+15 pad)
    int*      cnt     = gcur + 256 * GSTRIDE + 16;        // N
    float*    dinv    = (float*)(cnt + N);                // N
    int*      rowptr  = (int*)(dinv + N);                 // N
    int*      eidx    = rowptr + N;                       // E
    float4*   xs      = (float4*)(((uintptr_t)(eidx + E) + 15) & ~(uintptr_t)15);  // N
    uint32_t* Tp      = (uint32_t*)(xs + N);              // N*32 (layer-2 input, packed bf16)
    uint32_t* Tp2     = Tp + (size_t)N * 32;              // N*16 (layer-3 input, packed bf16)
    float*    gcnt    = (float*)(Tp2 + (size_t)N * 16);   // G
    uint32_t* staged  = Tp;                               // alias: dead before Tp written
    float*    out     = (float*)d_out;

    // ---- CSR build: multisplit stage -> per-bin fill ----
    hipMemsetAsync(gcur, 0, (256 * GSTRIDE + 16) * 4, stream);
    stage_ms_kernel<<<STAGE_BLOCKS, 256, 0, stream>>>(src, dst, gcur, staged, cap, nbins, E, chunk);
    fill_csr_kernel<<<nbins, 256, 0, stream>>>(staged, gcur, x, cap, nbins,
                                               rowptr, cnt, dinv, xs, eidx, N, out, gcnt, G);

    // ---- layer 1 + GEMM W2 fused: xs/CSR -> Tp (packed bf16) ----
    layer1_gemm2_kernel<<<(N + 31) / 32, 256, 0, stream>>>(
        xs, rowptr, cnt, eidx, dinv, W1, b1, g1, be1, rm1, rv1, W2, Tp, N);

    // ---- layer 2 gather + GEMM W3 fused: Tp/CSR -> Tp2 (packed bf16) ----
    layer2_gather_gemm3_kernel<<<(N + 31) / 32, 256, 0, stream>>>(
        Tp, rowptr, cnt, eidx, dinv, b2, g2, be2, rm2, rv2, W3, Tp2, N);

    // ---- layer 3 gather + mean-pool fused (+ last-block divide) ----
    layer3_gather_pool_kernel<<<(N + 63) / 64, 256, 0, stream>>>(
        Tp2, rowptr, cnt, eidx, dinv, batch, b3, g3, be3, rm3, rv3, out, gcnt, done, N, G);
}

// Round 7
// 236.764 us; speedup vs baseline: 5.4742x; 1.4787x over previous
//
#include <hip/hip_runtime.h>

#define EPS_BN 1e-5f
#define NEG_SLOPE 0.01f

#define BINSHIFT 9                 // 512 nodes per bin (BINSHIFT 7 regressed: R3)
#define BINSIZE (1 << BINSHIFT)
#define NBINS_LDS 200              // supports N up to 102400
#define BUFCAP 24                  // LDS records per (block,bin)
#define GSTRIDE 16                 // gcur padding: one counter per 64B line

// ---- bf16x2 pack/unpack (RNE) ----
__device__ __forceinline__ uint32_t pack2_bf16(float x, float y) {
    uint32_t ux = __float_as_uint(x);
    uint32_t uy = __float_as_uint(y);
    ux = (ux + 0x7fffu + ((ux >> 16) & 1u)) >> 16;
    uy = (uy + 0x7fffu + ((uy >> 16) & 1u)) >> 16;
    return (uy << 16) | (ux & 0xffffu);
}
__device__ __forceinline__ float bf_lo(uint32_t p) { return __uint_as_float(p << 16); }
__device__ __forceinline__ float bf_hi(uint32_t p) { return __uint_as_float(p & 0xffff0000u); }

// ---- phase A: LDS multisplit; 4 edges/thread/iter; packed 4-B records.
// rec = (src << BINSHIFT) | (dst & (BINSIZE-1)); src < 2^17 so 26 bits total.
// 4B records halve staged traffic AND stage LDS (40->21KB). R6's layer3
// fence regression reverted; this kernel kept (R7 isolates its effect).
__global__ void __launch_bounds__(256) stage_ms_kernel(
        const int* __restrict__ src, const int* __restrict__ dst,
        int* __restrict__ gcur, uint32_t* __restrict__ staged,
        int cap, int nbins, int E, int chunk) {
    __shared__ uint32_t bbuf[NBINS_LDS][BUFCAP];
    __shared__ int bcnt[NBINS_LDS];
    __shared__ int gpos[NBINS_LDS];
    for (int i = threadIdx.x; i < nbins; i += 256) bcnt[i] = 0;
    __syncthreads();
    int e0 = blockIdx.x * chunk;
    int e1 = min(e0 + chunk, E);
    for (int base = e0; base < e1; base += 1024) {       // 256 threads x 4 edges
        int e = base + threadIdx.x * 4;
        int s0, s1, s2, s3, d0, d1, d2, d3;
        int ne = 0;
        if (e + 4 <= e1) {
            int4 s4 = *(const int4*)(src + e);
            int4 d4 = *(const int4*)(dst + e);
            s0 = s4.x; s1 = s4.y; s2 = s4.z; s3 = s4.w;
            d0 = d4.x; d1 = d4.y; d2 = d4.z; d3 = d4.w;
            ne = 4;
        } else {
            int k = 0;
            for (; e + k < e1 && k < 4; ++k) {
                int sv = src[e + k], dv = dst[e + k];
                if (k == 0) { s0 = sv; d0 = dv; }
                else if (k == 1) { s1 = sv; d1 = dv; }
                else if (k == 2) { s2 = sv; d2 = dv; }
                else { s3 = sv; d3 = dv; }
            }
            ne = k;
        }
        #pragma unroll
        for (int k = 0; k < 4; ++k) {
            if (k >= ne) break;
            int s = (k == 0) ? s0 : (k == 1) ? s1 : (k == 2) ? s2 : s3;
            int d = (k == 0) ? d0 : (k == 1) ? d1 : (k == 2) ? d2 : d3;
            int bin = d >> BINSHIFT;
            uint32_t rec = ((uint32_t)s << BINSHIFT) | (uint32_t)(d & (BINSIZE - 1));
            int pos = atomicAdd(&bcnt[bin], 1);
            if (pos < BUFCAP) {
                bbuf[bin][pos] = rec;
            } else {                                     // rare: direct global append
                int gp = atomicAdd(&gcur[bin * GSTRIDE], 1);
                staged[(size_t)bin * cap + gp] = rec;
            }
        }
    }
    __syncthreads();
    // drain phase 1: one bin per THREAD -> all global atomics issue concurrently
    for (int b = threadIdx.x; b < nbins; b += 256) {
        int c = min(bcnt[b], BUFCAP);
        gpos[b] = (c > 0) ? atomicAdd(&gcur[b * GSTRIDE], c) : 0;
    }
    __syncthreads();
    // drain phase 2: cooperative 16-lane copy per bin
    int grp = threadIdx.x >> 4, lane = threadIdx.x & 15;
    for (int b = grp; b < nbins; b += 16) {
        int c = min(bcnt[b], BUFCAP);
        int gp = gpos[b];
        for (int i = lane; i < c; i += 16)
            staged[(size_t)b * cap + gp + i] = bbuf[b][i];
    }
}

// ---- phase B: per-bin CSR fill + rowptr/cnt/dinv/xs (packed recs).
// Block 0 also zeroes out/gcnt.
__global__ void __launch_bounds__(256) fill_csr_kernel(
        const uint32_t* __restrict__ staged, const int* __restrict__ gcur,
        const float* __restrict__ x, int cap, int nbins,
        int* __restrict__ rowptr, int* __restrict__ cnt,
        float* __restrict__ dinv, float4* __restrict__ xs,
        int* __restrict__ eidx, int N,
        float* __restrict__ out, float* __restrict__ gcnt, int G) {
    __shared__ int lcnt[BINSIZE];
    __shared__ int loff[BINSIZE];
    __shared__ int ps[256];
    int bin = blockIdx.x;
    // ---- binbase = sum of gcur[i] for i < bin ----
    int v = (threadIdx.x < nbins && threadIdx.x < bin) ? gcur[threadIdx.x * GSTRIDE] : 0;
    ps[threadIdx.x] = v;
    __syncthreads();
    for (int off = 128; off; off >>= 1) {
        if (threadIdx.x < off) ps[threadIdx.x] += ps[threadIdx.x + off];
        __syncthreads();
    }
    int bb = ps[0];
    __syncthreads();
    // ---- block 0: zero pool accumulators ----
    if (bin == 0) {
        for (int i = threadIdx.x; i < G * 32; i += 256) out[i] = 0.f;
        for (int i = threadIdx.x; i < G; i += 256) gcnt[i] = 0.f;
    }
    int node0 = bin << BINSHIFT;
    int nn = min(BINSIZE, N - node0);
    int nrec = gcur[bin * GSTRIDE];
    const uint32_t* recs = staged + (size_t)bin * cap;
    for (int i = threadIdx.x; i < BINSIZE; i += 256) lcnt[i] = 0;
    __syncthreads();
    for (int t = threadIdx.x; t < nrec; t += 256)
        atomicAdd(&lcnt[recs[t] & (BINSIZE - 1)], 1);
    __syncthreads();
    int p0 = lcnt[2 * threadIdx.x], p1 = lcnt[2 * threadIdx.x + 1];
    int pv = p0 + p1;
    ps[threadIdx.x] = pv;
    __syncthreads();
    for (int off = 1; off < 256; off <<= 1) {
        int t = (threadIdx.x >= off) ? ps[threadIdx.x - off] : 0;
        __syncthreads();
        ps[threadIdx.x] += t;
        __syncthreads();
    }
    int base = ps[threadIdx.x] - pv;
    loff[2 * threadIdx.x] = base;
    loff[2 * threadIdx.x + 1] = base + p0;
    __syncthreads();
    for (int i = threadIdx.x; i < nn; i += 256) {
        int node = node0 + i;
        rowptr[node] = bb + loff[i];
        cnt[node] = lcnt[i];
        float di = rsqrtf((float)(lcnt[i] + 1));         // +1 self-loop
        dinv[node] = di;
        const float* xr = x + (size_t)node * 3;
        xs[node] = make_float4(xr[0] * di, xr[1] * di, xr[2] * di, 0.f);
        lcnt[i] = 0;                                     // reuse as cursor
    }
    __syncthreads();
    for (int t = threadIdx.x; t < nrec; t += 256) {
        uint32_t r = recs[t];
        int li = r & (BINSIZE - 1);
        int p = atomicAdd(&lcnt[li], 1);
        eidx[bb + loff[li] + p] = (int)(r >> BINSHIFT);  // block-private range
    }
}

// ---- fused layer1 + GEMM(64->64) + dinv-scale + bf16 pack (R4 body) ----
__global__ void __launch_bounds__(256) layer1_gemm2_kernel(
        const float4* __restrict__ xs, const int* __restrict__ rowptr,
        const int* __restrict__ cnt, const int* __restrict__ eidx,
        const float* __restrict__ dinv, const float* __restrict__ W1,
        const float* __restrict__ b1, const float* __restrict__ g1,
        const float* __restrict__ be1, const float* __restrict__ rm1,
        const float* __restrict__ rv1, const float* __restrict__ W2,
        uint32_t* __restrict__ Tp, int N) {
    __shared__ float sW1[3 * 64];
    __shared__ float sSc[64], sSh[64];
    __shared__ float sW2[64 * 64];
    __shared__ float sH[32][64];
    __shared__ float sDinv[32];
    for (int i = threadIdx.x; i < 64 * 64; i += 256) sW2[i] = W2[i];
    if (threadIdx.x < 192) sW1[threadIdx.x] = W1[threadIdx.x];
    if (threadIdx.x < 64) {
        int f = threadIdx.x;
        float sc = rsqrtf(rv1[f] + EPS_BN) * g1[f];
        sSc[f] = sc;
        sSh[f] = (b1[f] - rm1[f]) * sc + be1[f];
    }
    __syncthreads();
    int lane = threadIdx.x & 7;
    int nl = threadIdx.x >> 3;                           // 0..31
    int node = blockIdx.x * 32 + nl;
    int m = min(node, N - 1);                            // clamp; no early return (sync below)
    int start = rowptr[m], deg = cnt[m];
    float ax = 0.f, ay = 0.f, az = 0.f;
    for (int j = lane; j < deg; j += 8) {
        float4 v = xs[eidx[start + j]];
        ax += v.x; ay += v.y; az += v.z;
    }
    #pragma unroll
    for (int o = 4; o; o >>= 1) {
        ax += __shfl_xor(ax, o, 8);
        ay += __shfl_xor(ay, o, 8);
        az += __shfl_xor(az, o, 8);
    }
    float4 self = xs[m];
    float di = dinv[m];
    float gx = (ax + self.x) * di, gy = (ay + self.y) * di, gz = (az + self.z) * di;
    if (lane == 0) sDinv[nl] = di;
    int f0 = lane * 8;
    #pragma unroll
    for (int hh = 0; hh < 2; ++hh) {
        float4 hv;
        #pragma unroll
        for (int q = 0; q < 4; ++q) {
            int f = f0 + 4 * hh + q;
            float a = gx * sW1[f] + gy * sW1[64 + f] + gz * sW1[128 + f];
            float y = a * sSc[f] + sSh[f];
            ((float*)&hv)[q] = (y >= 0.f) ? y : NEG_SLOPE * y;
        }
        *(float4*)&sH[nl][f0 + 4 * hh] = hv;
    }
    __syncthreads();
    int fp = threadIdx.x & 31;                           // feature pair 0..31
    int ng = threadIdx.x >> 5;                           // 0..7
    const float2* w2 = (const float2*)sW2 + fp;          // float2 stride 32 per k
    const float4* sH0 = (const float4*)&sH[ng][0];
    const float4* sH1 = (const float4*)&sH[ng + 8][0];
    const float4* sH2 = (const float4*)&sH[ng + 16][0];
    const float4* sH3 = (const float4*)&sH[ng + 24][0];
    float a00 = 0.f, a01 = 0.f, a10 = 0.f, a11 = 0.f;
    float a20 = 0.f, a21 = 0.f, a30 = 0.f, a31 = 0.f;
    #pragma unroll 4
    for (int k4 = 0; k4 < 16; ++k4) {
        float4 h0 = sH0[k4];
        float4 h1 = sH1[k4];
        float4 h2 = sH2[k4];
        float4 h3 = sH3[k4];
        float2 w;
        w = w2[(4 * k4 + 0) * 32];
        a00 = fmaf(h0.x, w.x, a00); a01 = fmaf(h0.x, w.y, a01);
        a10 = fmaf(h1.x, w.x, a10); a11 = fmaf(h1.x, w.y, a11);
        a20 = fmaf(h2.x, w.x, a20); a21 = fmaf(h2.x, w.y, a21);
        a30 = fmaf(h3.x, w.x, a30); a31 = fmaf(h3.x, w.y, a31);
        w = w2[(4 * k4 + 1) * 32];
        a00 = fmaf(h0.y, w.x, a00); a01 = fmaf(h0.y, w.y, a01);
        a10 = fmaf(h1.y, w.x, a10); a11 = fmaf(h1.y, w.y, a11);
        a20 = fmaf(h2.y, w.x, a20); a21 = fmaf(h2.y, w.y, a21);
        a30 = fmaf(h3.y, w.x, a30); a31 = fmaf(h3.y, w.y, a31);
        w = w2[(4 * k4 + 2) * 32];
        a00 = fmaf(h0.z, w.x, a00); a01 = fmaf(h0.z, w.y, a01);
        a10 = fmaf(h1.z, w.x, a10); a11 = fmaf(h1.z, w.y, a11);
        a20 = fmaf(h2.z, w.x, a20); a21 = fmaf(h2.z, w.y, a21);
        a30 = fmaf(h3.z, w.x, a30); a31 = fmaf(h3.z, w.y, a31);
        w = w2[(4 * k4 + 3) * 32];
        a00 = fmaf(h0.w, w.x, a00); a01 = fmaf(h0.w, w.y, a01);
        a10 = fmaf(h1.w, w.x, a10); a11 = fmaf(h1.w, w.y, a11);
        a20 = fmaf(h2.w, w.x, a20); a21 = fmaf(h2.w, w.y, a21);
        a30 = fmaf(h3.w, w.x, a30); a31 = fmaf(h3.w, w.y, a31);
    }
    int base = blockIdx.x * 32;
    int n0 = base + ng, n1 = base + ng + 8, n2 = base + ng + 16, n3 = base + ng + 24;
    if (n0 < N) { float d = sDinv[ng];      Tp[(size_t)n0 * 32 + fp] = pack2_bf16(a00 * d, a01 * d); }
    if (n1 < N) { float d = sDinv[ng + 8];  Tp[(size_t)n1 * 32 + fp] = pack2_bf16(a10 * d, a11 * d); }
    if (n2 < N) { float d = sDinv[ng + 16]; Tp[(size_t)n2 * 32 + fp] = pack2_bf16(a20 * d, a21 * d); }
    if (n3 < N) { float d = sDinv[ng + 24]; Tp[(size_t)n3 * 32 + fp] = pack2_bf16(a30 * d, a31 * d); }
}

// ---- fused layer-2 gather + BN2 + LReLU + GEMM(64->32) + dinv-scale + pack ----
__global__ void __launch_bounds__(256) layer2_gather_gemm3_kernel(
        const uint32_t* __restrict__ Tp, const int* __restrict__ rowptr,
        const int* __restrict__ cnt, const int* __restrict__ eidx,
        const float* __restrict__ dinv,
        const float* __restrict__ b2, const float* __restrict__ g2,
        const float* __restrict__ be2, const float* __restrict__ rm2,
        const float* __restrict__ rv2, const float* __restrict__ W3,
        uint32_t* __restrict__ Tp2, int N) {
    __shared__ float sW3[64 * 32];
    __shared__ float sSc[64], sSh[64];
    __shared__ float sH[32][64];
    __shared__ float sDinv[32];
    for (int i = threadIdx.x; i < 64 * 32; i += 256) sW3[i] = W3[i];
    if (threadIdx.x < 64) {
        int f = threadIdx.x;
        float sc = rsqrtf(rv2[f] + EPS_BN) * g2[f];
        sSc[f] = sc;
        sSh[f] = (b2[f] - rm2[f]) * sc + be2[f];
    }
    __syncthreads();
    int fq = threadIdx.x & 7;
    int nl = threadIdx.x >> 3;                           // 0..31
    int node = blockIdx.x * 32 + nl;
    int m = min(node, N - 1);
    const uint4* T4 = (const uint4*)Tp + fq;             // stride 8 uint4 per node
    int start = rowptr[m];
    int deg = cnt[m];
    uint4 ts = T4[(size_t)m * 8];
    float a0 = bf_lo(ts.x), a1 = bf_hi(ts.x), a2 = bf_lo(ts.y), a3 = bf_hi(ts.y);
    float a4 = bf_lo(ts.z), a5 = bf_hi(ts.z), a6 = bf_lo(ts.w), a7 = bf_hi(ts.w);
    float c0 = 0.f, c1 = 0.f, c2 = 0.f, c3 = 0.f;
    float c4 = 0.f, c5 = 0.f, c6 = 0.f, c7 = 0.f;
    const int* ep = eidx + start;
    int j = 0;
    for (; j + 4 <= deg; j += 4) {
        int s0 = ep[j], s1 = ep[j + 1], s2 = ep[j + 2], s3 = ep[j + 3];
        uint4 t0 = T4[(size_t)s0 * 8];
        uint4 t1 = T4[(size_t)s1 * 8];
        uint4 t2 = T4[(size_t)s2 * 8];
        uint4 t3 = T4[(size_t)s3 * 8];
        a0 += bf_lo(t0.x) + bf_lo(t2.x);  a1 += bf_hi(t0.x) + bf_hi(t2.x);
        a2 += bf_lo(t0.y) + bf_lo(t2.y);  a3 += bf_hi(t0.y) + bf_hi(t2.y);
        a4 += bf_lo(t0.z) + bf_lo(t2.z);  a5 += bf_hi(t0.z) + bf_hi(t2.z);
        a6 += bf_lo(t0.w) + bf_lo(t2.w);  a7 += bf_hi(t0.w) + bf_hi(t2.w);
        c0 += bf_lo(t1.x) + bf_lo(t3.x);  c1 += bf_hi(t1.x) + bf_hi(t3.x);
        c2 += bf_lo(t1.y) + bf_lo(t3.y);  c3 += bf_hi(t1.y) + bf_hi(t3.y);
        c4 += bf_lo(t1.z) + bf_lo(t3.z);  c5 += bf_hi(t1.z) + bf_hi(t3.z);
        c6 += bf_lo(t1.w) + bf_lo(t3.w);  c7 += bf_hi(t1.w) + bf_hi(t3.w);
    }
    for (; j < deg; ++j) {
        uint4 t0 = T4[(size_t)ep[j] * 8];
        a0 += bf_lo(t0.x); a1 += bf_hi(t0.x);
        a2 += bf_lo(t0.y); a3 += bf_hi(t0.y);
        a4 += bf_lo(t0.z); a5 += bf_hi(t0.z);
        a6 += bf_lo(t0.w); a7 += bf_hi(t0.w);
    }
    float di = dinv[m];
    if (fq == 0) sDinv[nl] = di;
    int f0 = 8 * fq;
    float av[8] = {a0 + c0, a1 + c1, a2 + c2, a3 + c3,
                   a4 + c4, a5 + c5, a6 + c6, a7 + c7};
    #pragma unroll
    for (int hh = 0; hh < 2; ++hh) {
        float4 hv;
        #pragma unroll
        for (int q = 0; q < 4; ++q) {
            int f = f0 + 4 * hh + q;
            float y = av[4 * hh + q] * di * sSc[f] + sSh[f];
            ((float*)&hv)[q] = (y >= 0.f) ? y : NEG_SLOPE * y;
        }
        *(float4*)&sH[nl][f0 + 4 * hh] = hv;
    }
    __syncthreads();
    int fp = threadIdx.x & 15;                           // feature pair 0..15
    int ng = threadIdx.x >> 4;                           // 0..15
    const float2* w3 = (const float2*)sW3 + fp;          // float2 stride 16 per k
    const float4* sHA = (const float4*)&sH[ng][0];
    const float4* sHB = (const float4*)&sH[ng + 16][0];
    float p0 = 0.f, p1 = 0.f, q0 = 0.f, q1 = 0.f;
    #pragma unroll 4
    for (int k4 = 0; k4 < 16; ++k4) {
        float4 hA = sHA[k4];
        float4 hB = sHB[k4];
        float2 w;
        w = w3[(4 * k4 + 0) * 16];
        p0 = fmaf(hA.x, w.x, p0); p1 = fmaf(hA.x, w.y, p1);
        q0 = fmaf(hB.x, w.x, q0); q1 = fmaf(hB.x, w.y, q1);
        w = w3[(4 * k4 + 1) * 16];
        p0 = fmaf(hA.y, w.x, p0); p1 = fmaf(hA.y, w.y, p1);
        q0 = fmaf(hB.y, w.x, q0); q1 = fmaf(hB.y, w.y, q1);
        w = w3[(4 * k4 + 2) * 16];
        p0 = fmaf(hA.z, w.x, p0); p1 = fmaf(hA.z, w.y, p1);
        q0 = fmaf(hB.z, w.x, q0); q1 = fmaf(hB.z, w.y, q1);
        w = w3[(4 * k4 + 3) * 16];
        p0 = fmaf(hA.w, w.x, p0); p1 = fmaf(hA.w, w.y, p1);
        q0 = fmaf(hB.w, w.x, q0); q1 = fmaf(hB.w, w.y, q1);
    }
    int base = blockIdx.x * 32;
    int nA = base + ng, nB = base + ng + 16;
    if (nA < N) { float d = sDinv[ng];      Tp2[(size_t)nA * 16 + fp] = pack2_bf16(p0 * d, p1 * d); }
    if (nB < N) { float d = sDinv[ng + 16]; Tp2[(size_t)nB * 16 + fp] = pack2_bf16(q0 * d, q1 * d); }
}

// ---- fused layer-3 gather + BN3 + LReLU + mean-pool accumulate (R4 body;
// R6's threadfence+ticket epilogue REMOVED -- device-scope fences per block
// invalidate L2 across the chip and re-missed every Tp2 gather: 141us vs 44) ----
#define SLOTS 16
__global__ void __launch_bounds__(256) layer3_gather_pool_kernel(
        const uint32_t* __restrict__ Tp2, const int* __restrict__ rowptr,
        const int* __restrict__ cnt, const int* __restrict__ eidx,
        const float* __restrict__ dinv, const int* __restrict__ batch,
        const float* __restrict__ b3, const float* __restrict__ g3,
        const float* __restrict__ be3, const float* __restrict__ rm3,
        const float* __restrict__ rv3,
        float* __restrict__ out, float* __restrict__ gcnt, int N) {
    __shared__ float sSc[32], sSh[32];
    __shared__ float sAcc[SLOTS][32];
    __shared__ int sCnt[SLOTS];
    if (threadIdx.x < 32) {
        int f = threadIdx.x;
        float sc = rsqrtf(rv3[f] + EPS_BN) * g3[f];
        sSc[f] = sc;
        sSh[f] = (b3[f] - rm3[f]) * sc + be3[f];
    }
    for (int i = threadIdx.x; i < SLOTS * 32; i += 256) ((float*)sAcc)[i] = 0.f;
    if (threadIdx.x < SLOTS) sCnt[threadIdx.x] = 0;
    __syncthreads();
    int fq = threadIdx.x & 3;
    int nl = threadIdx.x >> 2;                           // 0..63
    int node = blockIdx.x * 64 + nl;
    bool valid = node < N;
    int m = valid ? node : N - 1;
    const uint4* T4 = (const uint4*)Tp2 + fq;            // stride 4 uint4 per node
    int start = rowptr[m];
    int deg = cnt[m];
    uint4 ts = T4[(size_t)m * 4];
    float a0 = bf_lo(ts.x), a1 = bf_hi(ts.x), a2 = bf_lo(ts.y), a3 = bf_hi(ts.y);
    float a4 = bf_lo(ts.z), a5 = bf_hi(ts.z), a6 = bf_lo(ts.w), a7 = bf_hi(ts.w);
    float c0 = 0.f, c1 = 0.f, c2 = 0.f, c3 = 0.f;
    float c4 = 0.f, c5 = 0.f, c6 = 0.f, c7 = 0.f;
    const int* ep = eidx + start;
    int j = 0;
    for (; j + 4 <= deg; j += 4) {
        int s0 = ep[j], s1 = ep[j + 1], s2 = ep[j + 2], s3 = ep[j + 3];
        uint4 t0 = T4[(size_t)s0 * 4];
        uint4 t1 = T4[(size_t)s1 * 4];
        uint4 t2 = T4[(size_t)s2 * 4];
        uint4 t3 = T4[(size_t)s3 * 4];
        a0 += bf_lo(t0.x) + bf_lo(t2.x);  a1 += bf_hi(t0.x) + bf_hi(t2.x);
        a2 += bf_lo(t0.y) + bf_lo(t2.y);  a3 += bf_hi(t0.y) + bf_hi(t2.y);
        a4 += bf_lo(t0.z) + bf_lo(t2.z);  a5 += bf_hi(t0.z) + bf_hi(t2.z);
        a6 += bf_lo(t0.w) + bf_lo(t2.w);  a7 += bf_hi(t0.w) + bf_hi(t2.w);
        c0 += bf_lo(t1.x) + bf_lo(t3.x);  c1 += bf_hi(t1.x) + bf_hi(t3.x);
        c2 += bf_lo(t1.y) + bf_lo(t3.y);  c3 += bf_hi(t1.y) + bf_hi(t3.y);
        c4 += bf_lo(t1.z) + bf_lo(t3.z);  c5 += bf_hi(t1.z) + bf_hi(t3.z);
        c6 += bf_lo(t1.w) + bf_lo(t3.w);  c7 += bf_hi(t1.w) + bf_hi(t3.w);
    }
    for (; j < deg; ++j) {
        uint4 t0 = T4[(size_t)ep[j] * 4];
        a0 += bf_lo(t0.x); a1 += bf_hi(t0.x);
        a2 += bf_lo(t0.y); a3 += bf_hi(t0.y);
        a4 += bf_lo(t0.z); a5 += bf_hi(t0.z);
        a6 += bf_lo(t0.w); a7 += bf_hi(t0.w);
    }
    float di = dinv[m];
    int f0 = 8 * fq;
    float av[8] = {a0 + c0, a1 + c1, a2 + c2, a3 + c3,
                   a4 + c4, a5 + c5, a6 + c6, a7 + c7};
    float y[8];
    #pragma unroll
    for (int q = 0; q < 8; ++q) {
        float yy = av[q] * di * sSc[f0 + q] + sSh[f0 + q];
        y[q] = (yy >= 0.f) ? yy : NEG_SLOPE * yy;
    }
    int g0 = batch[blockIdx.x * 64];                     // first node of block, always < N
    if (valid) {
        int g = batch[node];
        int slot = g - g0;
        if (slot < SLOTS) {
            #pragma unroll
            for (int q = 0; q < 8; ++q) atomicAdd(&sAcc[slot][f0 + q], y[q]);
            if (fq == 0) atomicAdd(&sCnt[slot], 1);
        } else {                                         // rare: block spans many graphs
            #pragma unroll
            for (int q = 0; q < 8; ++q) atomicAdd(&out[(g << 5) + f0 + q], y[q]);
            if (fq == 0) atomicAdd(&gcnt[g], 1.f);
        }
    }
    __syncthreads();
    for (int i = threadIdx.x; i < SLOTS * 32; i += 256) {
        int s = i >> 5;
        if (sCnt[s] > 0)
            atomicAdd(&out[((g0 + s) << 5) + (i & 31)], ((float*)sAcc)[i]);
    }
    if (threadIdx.x < SLOTS && sCnt[threadIdx.x] > 0)
        atomicAdd(&gcnt[g0 + threadIdx.x], (float)sCnt[threadIdx.x]);
}

__global__ void pool_div_kernel(float* __restrict__ out, const float* __restrict__ gcnt, int G) {
    int tid = blockIdx.x * blockDim.x + threadIdx.x;
    if (tid < (G << 5)) out[tid] /= fmaxf(gcnt[tid >> 5], 1.0f);
}

extern "C" void kernel_launch(void* const* d_in, const int* in_sizes, int n_in,
                              void* d_out, int out_size, void* d_ws, size_t ws_size,
                              hipStream_t stream) {
    const float* x   = (const float*)d_in[0];
    const float* W1  = (const float*)d_in[1];
    const float* b1  = (const float*)d_in[2];
    const float* g1  = (const float*)d_in[3];
    const float* be1 = (const float*)d_in[4];
    const float* rm1 = (const float*)d_in[5];
    const float* rv1 = (const float*)d_in[6];
    const float* W2  = (const float*)d_in[7];
    const float* b2  = (const float*)d_in[8];
    const float* g2  = (const float*)d_in[9];
    const float* be2 = (const float*)d_in[10];
    const float* rm2 = (const float*)d_in[11];
    const float* rv2 = (const float*)d_in[12];
    const float* W3  = (const float*)d_in[13];
    const float* b3  = (const float*)d_in[14];
    const float* g3  = (const float*)d_in[15];
    const float* be3 = (const float*)d_in[16];
    const float* rm3 = (const float*)d_in[17];
    const float* rv3 = (const float*)d_in[18];
    const int* ei    = (const int*)d_in[19];
    const int* batch = (const int*)d_in[20];

    const int N = in_sizes[0] / 3;
    const int E = in_sizes[19] / 2;
    const int G = out_size / 32;
    const int* src = ei;
    const int* dst = ei + E;

    const int B = 256;
    const int nbins = (N + BINSIZE - 1) >> BINSHIFT;                  // 196 for N=100k
    const int cap = (((E / nbins) * 3) / 2 + 15) & ~15;               // 1.5x mean
    const int STAGE_BLOCKS = 512;
    const int chunk = (((E + STAGE_BLOCKS - 1) / STAGE_BLOCKS) + 3) & ~3;  // 4-aligned

    // workspace layout (staged aliases Tp, dead before layer1_gemm2 writes Tp)
    int*      gcur    = (int*)d_ws;                       // 256*GSTRIDE
    int*      cnt     = gcur + 256 * GSTRIDE;             // N
    float*    dinv    = (float*)(cnt + N);                // N
    int*      rowptr  = (int*)(dinv + N);                 // N
    int*      eidx    = rowptr + N;                       // E
    float4*   xs      = (float4*)(((uintptr_t)(eidx + E) + 15) & ~(uintptr_t)15);  // N
    uint32_t* Tp      = (uint32_t*)(xs + N);              // N*32 (layer-2 input, packed bf16)
    uint32_t* Tp2     = Tp + (size_t)N * 32;              // N*16 (layer-3 input, packed bf16)
    float*    gcnt    = (float*)(Tp2 + (size_t)N * 16);   // G
    uint32_t* staged  = Tp;                               // alias: dead before Tp written
    float*    out     = (float*)d_out;

    // ---- CSR build: multisplit stage -> per-bin fill ----
    hipMemsetAsync(gcur, 0, 256 * GSTRIDE * 4, stream);
    stage_ms_kernel<<<STAGE_BLOCKS, 256, 0, stream>>>(src, dst, gcur, staged, cap, nbins, E, chunk);
    fill_csr_kernel<<<nbins, 256, 0, stream>>>(staged, gcur, x, cap, nbins,
                                               rowptr, cnt, dinv, xs, eidx, N, out, gcnt, G);

    // ---- layer 1 + GEMM W2 fused: xs/CSR -> Tp (packed bf16) ----
    layer1_gemm2_kernel<<<(N + 31) / 32, 256, 0, stream>>>(
        xs, rowptr, cnt, eidx, dinv, W1, b1, g1, be1, rm1, rv1, W2, Tp, N);

    // ---- layer 2 gather + GEMM W3 fused: Tp/CSR -> Tp2 (packed bf16) ----
    layer2_gather_gemm3_kernel<<<(N + 31) / 32, 256, 0, stream>>>(
        Tp, rowptr, cnt, eidx, dinv, b2, g2, be2, rm2, rv2, W3, Tp2, N);

    // ---- layer 3 gather + mean-pool fused: Tp2/CSR -> out/gcnt atomics ----
    layer3_gather_pool_kernel<<<(N + 63) / 64, 256, 0, stream>>>(
        Tp2, rowptr, cnt, eidx, dinv, batch, b3, g3, be3, rm3, rv3, out, gcnt, N);

    pool_div_kernel<<<(G * 32 + B - 1) / B, B, 0, stream>>>(out, gcnt, G);
}

// Round 8
// 233.888 us; speedup vs baseline: 5.5415x; 1.0123x over previous
//
#include <hip/hip_runtime.h>

#define EPS_BN 1e-5f
#define NEG_SLOPE 0.01f

#define BINSHIFT 9                 // 512 nodes per bin (BINSHIFT 7 regressed: R3)
#define BINSIZE (1 << BINSHIFT)
#define NBINS_LDS 200              // supports N up to 102400
#define BUFCAP 24                  // LDS records per (block,bin)
#define GSTRIDE 16                 // gcur padding: one counter per 64B line

// ---- bf16x2 pack/unpack (RNE) ----
__device__ __forceinline__ uint32_t pack2_bf16(float x, float y) {
    uint32_t ux = __float_as_uint(x);
    uint32_t uy = __float_as_uint(y);
    ux = (ux + 0x7fffu + ((ux >> 16) & 1u)) >> 16;
    uy = (uy + 0x7fffu + ((uy >> 16) & 1u)) >> 16;
    return (uy << 16) | (ux & 0xffffu);
}
__device__ __forceinline__ float bf_lo(uint32_t p) { return __uint_as_float(p << 16); }
__device__ __forceinline__ float bf_hi(uint32_t p) { return __uint_as_float(p & 0xffff0000u); }

// ---- phase A: LDS multisplit; 4 edges/thread/iter; packed 4-B records ----
__global__ void __launch_bounds__(256) stage_ms_kernel(
        const int* __restrict__ src, const int* __restrict__ dst,
        int* __restrict__ gcur, uint32_t* __restrict__ staged,
        int cap, int nbins, int E, int chunk) {
    __shared__ uint32_t bbuf[NBINS_LDS][BUFCAP];
    __shared__ int bcnt[NBINS_LDS];
    __shared__ int gpos[NBINS_LDS];
    for (int i = threadIdx.x; i < nbins; i += 256) bcnt[i] = 0;
    __syncthreads();
    int e0 = blockIdx.x * chunk;
    int e1 = min(e0 + chunk, E);
    for (int base = e0; base < e1; base += 1024) {       // 256 threads x 4 edges
        int e = base + threadIdx.x * 4;
        int s0, s1, s2, s3, d0, d1, d2, d3;
        int ne = 0;
        if (e + 4 <= e1) {
            int4 s4 = *(const int4*)(src + e);
            int4 d4 = *(const int4*)(dst + e);
            s0 = s4.x; s1 = s4.y; s2 = s4.z; s3 = s4.w;
            d0 = d4.x; d1 = d4.y; d2 = d4.z; d3 = d4.w;
            ne = 4;
        } else {
            int k = 0;
            for (; e + k < e1 && k < 4; ++k) {
                int sv = src[e + k], dv = dst[e + k];
                if (k == 0) { s0 = sv; d0 = dv; }
                else if (k == 1) { s1 = sv; d1 = dv; }
                else if (k == 2) { s2 = sv; d2 = dv; }
                else { s3 = sv; d3 = dv; }
            }
            ne = k;
        }
        #pragma unroll
        for (int k = 0; k < 4; ++k) {
            if (k >= ne) break;
            int s = (k == 0) ? s0 : (k == 1) ? s1 : (k == 2) ? s2 : s3;
            int d = (k == 0) ? d0 : (k == 1) ? d1 : (k == 2) ? d2 : d3;
            int bin = d >> BINSHIFT;
            uint32_t rec = ((uint32_t)s << BINSHIFT) | (uint32_t)(d & (BINSIZE - 1));
            int pos = atomicAdd(&bcnt[bin], 1);
            if (pos < BUFCAP) {
                bbuf[bin][pos] = rec;
            } else {                                     // rare: direct global append
                int gp = atomicAdd(&gcur[bin * GSTRIDE], 1);
                staged[(size_t)bin * cap + gp] = rec;
            }
        }
    }
    __syncthreads();
    // drain phase 1: one bin per THREAD -> all global atomics issue concurrently
    for (int b = threadIdx.x; b < nbins; b += 256) {
        int c = min(bcnt[b], BUFCAP);
        gpos[b] = (c > 0) ? atomicAdd(&gcur[b * GSTRIDE], c) : 0;
    }
    __syncthreads();
    // drain phase 2: cooperative 16-lane copy per bin
    int grp = threadIdx.x >> 4, lane = threadIdx.x & 15;
    for (int b = grp; b < nbins; b += 16) {
        int c = min(bcnt[b], BUFCAP);
        int gp = gpos[b];
        for (int i = lane; i < c; i += 16)
            staged[(size_t)b * cap + gp + i] = bbuf[b][i];
    }
}

// ---- phase B: per-bin CSR fill + rowptr/cnt/dinv/xs (packed recs) ----
__global__ void __launch_bounds__(256) fill_csr_kernel(
        const uint32_t* __restrict__ staged, const int* __restrict__ gcur,
        const float* __restrict__ x, int cap, int nbins,
        int* __restrict__ rowptr, int* __restrict__ cnt,
        float* __restrict__ dinv, float4* __restrict__ xs,
        int* __restrict__ eidx, int N,
        float* __restrict__ out, float* __restrict__ gcnt, int G) {
    __shared__ int lcnt[BINSIZE];
    __shared__ int loff[BINSIZE];
    __shared__ int ps[256];
    int bin = blockIdx.x;
    // ---- binbase = sum of gcur[i] for i < bin ----
    int v = (threadIdx.x < nbins && threadIdx.x < bin) ? gcur[threadIdx.x * GSTRIDE] : 0;
    ps[threadIdx.x] = v;
    __syncthreads();
    for (int off = 128; off; off >>= 1) {
        if (threadIdx.x < off) ps[threadIdx.x] += ps[threadIdx.x + off];
        __syncthreads();
    }
    int bb = ps[0];
    __syncthreads();
    // ---- block 0: zero pool accumulators ----
    if (bin == 0) {
        for (int i = threadIdx.x; i < G * 32; i += 256) out[i] = 0.f;
        for (int i = threadIdx.x; i < G; i += 256) gcnt[i] = 0.f;
    }
    int node0 = bin << BINSHIFT;
    int nn = min(BINSIZE, N - node0);
    int nrec = gcur[bin * GSTRIDE];
    const uint32_t* recs = staged + (size_t)bin * cap;
    for (int i = threadIdx.x; i < BINSIZE; i += 256) lcnt[i] = 0;
    __syncthreads();
    for (int t = threadIdx.x; t < nrec; t += 256)
        atomicAdd(&lcnt[recs[t] & (BINSIZE - 1)], 1);
    __syncthreads();
    int p0 = lcnt[2 * threadIdx.x], p1 = lcnt[2 * threadIdx.x + 1];
    int pv = p0 + p1;
    ps[threadIdx.x] = pv;
    __syncthreads();
    for (int off = 1; off < 256; off <<= 1) {
        int t = (threadIdx.x >= off) ? ps[threadIdx.x - off] : 0;
        __syncthreads();
        ps[threadIdx.x] += t;
        __syncthreads();
    }
    int base = ps[threadIdx.x] - pv;
    loff[2 * threadIdx.x] = base;
    loff[2 * threadIdx.x + 1] = base + p0;
    __syncthreads();
    for (int i = threadIdx.x; i < nn; i += 256) {
        int node = node0 + i;
        rowptr[node] = bb + loff[i];
        cnt[node] = lcnt[i];
        float di = rsqrtf((float)(lcnt[i] + 1));         // +1 self-loop
        dinv[node] = di;
        const float* xr = x + (size_t)node * 3;
        xs[node] = make_float4(xr[0] * di, xr[1] * di, xr[2] * di, 0.f);
        lcnt[i] = 0;                                     // reuse as cursor
    }
    __syncthreads();
    for (int t = threadIdx.x; t < nrec; t += 256) {
        uint32_t r = recs[t];
        int li = r & (BINSIZE - 1);
        int p = atomicAdd(&lcnt[li], 1);
        eidx[bb + loff[li] + p] = (int)(r >> BINSHIFT);  // block-private range
    }
}

// ---- fused layer1 + GEMM(64->64) + dinv-scale + bf16 pack (R4 body) ----
__global__ void __launch_bounds__(256) layer1_gemm2_kernel(
        const float4* __restrict__ xs, const int* __restrict__ rowptr,
        const int* __restrict__ cnt, const int* __restrict__ eidx,
        const float* __restrict__ dinv, const float* __restrict__ W1,
        const float* __restrict__ b1, const float* __restrict__ g1,
        const float* __restrict__ be1, const float* __restrict__ rm1,
        const float* __restrict__ rv1, const float* __restrict__ W2,
        uint32_t* __restrict__ Tp, int N) {
    __shared__ float sW1[3 * 64];
    __shared__ float sSc[64], sSh[64];
    __shared__ float sW2[64 * 64];
    __shared__ float sH[32][64];
    __shared__ float sDinv[32];
    for (int i = threadIdx.x; i < 64 * 64; i += 256) sW2[i] = W2[i];
    if (threadIdx.x < 192) sW1[threadIdx.x] = W1[threadIdx.x];
    if (threadIdx.x < 64) {
        int f = threadIdx.x;
        float sc = rsqrtf(rv1[f] + EPS_BN) * g1[f];
        sSc[f] = sc;
        sSh[f] = (b1[f] - rm1[f]) * sc + be1[f];
    }
    __syncthreads();
    int lane = threadIdx.x & 7;
    int nl = threadIdx.x >> 3;                           // 0..31
    int node = blockIdx.x * 32 + nl;
    int m = min(node, N - 1);                            // clamp; no early return (sync below)
    int start = rowptr[m], deg = cnt[m];
    float ax = 0.f, ay = 0.f, az = 0.f;
    for (int j = lane; j < deg; j += 8) {
        float4 v = xs[eidx[start + j]];
        ax += v.x; ay += v.y; az += v.z;
    }
    #pragma unroll
    for (int o = 4; o; o >>= 1) {
        ax += __shfl_xor(ax, o, 8);
        ay += __shfl_xor(ay, o, 8);
        az += __shfl_xor(az, o, 8);
    }
    float4 self = xs[m];
    float di = dinv[m];
    float gx = (ax + self.x) * di, gy = (ay + self.y) * di, gz = (az + self.z) * di;
    if (lane == 0) sDinv[nl] = di;
    int f0 = lane * 8;
    #pragma unroll
    for (int hh = 0; hh < 2; ++hh) {
        float4 hv;
        #pragma unroll
        for (int q = 0; q < 4; ++q) {
            int f = f0 + 4 * hh + q;
            float a = gx * sW1[f] + gy * sW1[64 + f] + gz * sW1[128 + f];
            float y = a * sSc[f] + sSh[f];
            ((float*)&hv)[q] = (y >= 0.f) ? y : NEG_SLOPE * y;
        }
        *(float4*)&sH[nl][f0 + 4 * hh] = hv;
    }
    __syncthreads();
    int fp = threadIdx.x & 31;                           // feature pair 0..31
    int ng = threadIdx.x >> 5;                           // 0..7
    const float2* w2 = (const float2*)sW2 + fp;          // float2 stride 32 per k
    const float4* sH0 = (const float4*)&sH[ng][0];
    const float4* sH1 = (const float4*)&sH[ng + 8][0];
    const float4* sH2 = (const float4*)&sH[ng + 16][0];
    const float4* sH3 = (const float4*)&sH[ng + 24][0];
    float a00 = 0.f, a01 = 0.f, a10 = 0.f, a11 = 0.f;
    float a20 = 0.f, a21 = 0.f, a30 = 0.f, a31 = 0.f;
    #pragma unroll 4
    for (int k4 = 0; k4 < 16; ++k4) {
        float4 h0 = sH0[k4];
        float4 h1 = sH1[k4];
        float4 h2 = sH2[k4];
        float4 h3 = sH3[k4];
        float2 w;
        w = w2[(4 * k4 + 0) * 32];
        a00 = fmaf(h0.x, w.x, a00); a01 = fmaf(h0.x, w.y, a01);
        a10 = fmaf(h1.x, w.x, a10); a11 = fmaf(h1.x, w.y, a11);
        a20 = fmaf(h2.x, w.x, a20); a21 = fmaf(h2.x, w.y, a21);
        a30 = fmaf(h3.x, w.x, a30); a31 = fmaf(h3.x, w.y, a31);
        w = w2[(4 * k4 + 1) * 32];
        a00 = fmaf(h0.y, w.x, a00); a01 = fmaf(h0.y, w.y, a01);
        a10 = fmaf(h1.y, w.x, a10); a11 = fmaf(h1.y, w.y, a11);
        a20 = fmaf(h2.y, w.x, a20); a21 = fmaf(h2.y, w.y, a21);
        a30 = fmaf(h3.y, w.x, a30); a31 = fmaf(h3.y, w.y, a31);
        w = w2[(4 * k4 + 2) * 32];
        a00 = fmaf(h0.z, w.x, a00); a01 = fmaf(h0.z, w.y, a01);
        a10 = fmaf(h1.z, w.x, a10); a11 = fmaf(h1.z, w.y, a11);
        a20 = fmaf(h2.z, w.x, a20); a21 = fmaf(h2.z, w.y, a21);
        a30 = fmaf(h3.z, w.x, a30); a31 = fmaf(h3.z, w.y, a31);
        w = w2[(4 * k4 + 3) * 32];
        a00 = fmaf(h0.w, w.x, a00); a01 = fmaf(h0.w, w.y, a01);
        a10 = fmaf(h1.w, w.x, a10); a11 = fmaf(h1.w, w.y, a11);
        a20 = fmaf(h2.w, w.x, a20); a21 = fmaf(h2.w, w.y, a21);
        a30 = fmaf(h3.w, w.x, a30); a31 = fmaf(h3.w, w.y, a31);
    }
    int base = blockIdx.x * 32;
    int n0 = base + ng, n1 = base + ng + 8, n2 = base + ng + 16, n3 = base + ng + 24;
    if (n0 < N) { float d = sDinv[ng];      Tp[(size_t)n0 * 32 + fp] = pack2_bf16(a00 * d, a01 * d); }
    if (n1 < N) { float d = sDinv[ng + 8];  Tp[(size_t)n1 * 32 + fp] = pack2_bf16(a10 * d, a11 * d); }
    if (n2 < N) { float d = sDinv[ng + 16]; Tp[(size_t)n2 * 32 + fp] = pack2_bf16(a20 * d, a21 * d); }
    if (n3 < N) { float d = sDinv[ng + 24]; Tp[(size_t)n3 * 32 + fp] = pack2_bf16(a30 * d, a31 * d); }
}

// ---- fused layer-2 gather + BN2 + LReLU + GEMM(64->32) + dinv-scale + pack.
// R8: software-pipelined gather -- next iteration's 4 eidx values load while
// the current 4 T4 gathers are in flight (breaks the eidx->gather serial
// chain, ~200cy/iter). Accumulation order unchanged -> bit-identical.
__global__ void __launch_bounds__(256) layer2_gather_gemm3_kernel(
        const uint32_t* __restrict__ Tp, const int* __restrict__ rowptr,
        const int* __restrict__ cnt, const int* __restrict__ eidx,
        const float* __restrict__ dinv,
        const float* __restrict__ b2, const float* __restrict__ g2,
        const float* __restrict__ be2, const float* __restrict__ rm2,
        const float* __restrict__ rv2, const float* __restrict__ W3,
        uint32_t* __restrict__ Tp2, int N) {
    __shared__ float sW3[64 * 32];
    __shared__ float sSc[64], sSh[64];
    __shared__ float sH[32][64];
    __shared__ float sDinv[32];
    for (int i = threadIdx.x; i < 64 * 32; i += 256) sW3[i] = W3[i];
    if (threadIdx.x < 64) {
        int f = threadIdx.x;
        float sc = rsqrtf(rv2[f] + EPS_BN) * g2[f];
        sSc[f] = sc;
        sSh[f] = (b2[f] - rm2[f]) * sc + be2[f];
    }
    __syncthreads();
    int fq = threadIdx.x & 7;
    int nl = threadIdx.x >> 3;                           // 0..31
    int node = blockIdx.x * 32 + nl;
    int m = min(node, N - 1);
    const uint4* T4 = (const uint4*)Tp + fq;             // stride 8 uint4 per node
    int start = rowptr[m];
    int deg = cnt[m];
    uint4 ts = T4[(size_t)m * 8];
    float a0 = bf_lo(ts.x), a1 = bf_hi(ts.x), a2 = bf_lo(ts.y), a3 = bf_hi(ts.y);
    float a4 = bf_lo(ts.z), a5 = bf_hi(ts.z), a6 = bf_lo(ts.w), a7 = bf_hi(ts.w);
    float c0 = 0.f, c1 = 0.f, c2 = 0.f, c3 = 0.f;
    float c4 = 0.f, c5 = 0.f, c6 = 0.f, c7 = 0.f;
    const int* ep = eidx + start;
    int j = 0;
    int s0, s1, s2, s3;
    if (deg >= 4) { s0 = ep[0]; s1 = ep[1]; s2 = ep[2]; s3 = ep[3]; }
    for (; j + 8 <= deg; j += 4) {                       // pipelined: prefetch j+4..j+7
        uint4 t0 = T4[(size_t)s0 * 8];
        uint4 t1 = T4[(size_t)s1 * 8];
        uint4 t2 = T4[(size_t)s2 * 8];
        uint4 t3 = T4[(size_t)s3 * 8];
        s0 = ep[j + 4]; s1 = ep[j + 5]; s2 = ep[j + 6]; s3 = ep[j + 7];
        a0 += bf_lo(t0.x) + bf_lo(t2.x);  a1 += bf_hi(t0.x) + bf_hi(t2.x);
        a2 += bf_lo(t0.y) + bf_lo(t2.y);  a3 += bf_hi(t0.y) + bf_hi(t2.y);
        a4 += bf_lo(t0.z) + bf_lo(t2.z);  a5 += bf_hi(t0.z) + bf_hi(t2.z);
        a6 += bf_lo(t0.w) + bf_lo(t2.w);  a7 += bf_hi(t0.w) + bf_hi(t2.w);
        c0 += bf_lo(t1.x) + bf_lo(t3.x);  c1 += bf_hi(t1.x) + bf_hi(t3.x);
        c2 += bf_lo(t1.y) + bf_lo(t3.y);  c3 += bf_hi(t1.y) + bf_hi(t3.y);
        c4 += bf_lo(t1.z) + bf_lo(t3.z);  c5 += bf_hi(t1.z) + bf_hi(t3.z);
        c6 += bf_lo(t1.w) + bf_lo(t3.w);  c7 += bf_hi(t1.w) + bf_hi(t3.w);
    }
    if (j + 4 <= deg) {                                  // drain the prefetched quad
        uint4 t0 = T4[(size_t)s0 * 8];
        uint4 t1 = T4[(size_t)s1 * 8];
        uint4 t2 = T4[(size_t)s2 * 8];
        uint4 t3 = T4[(size_t)s3 * 8];
        a0 += bf_lo(t0.x) + bf_lo(t2.x);  a1 += bf_hi(t0.x) + bf_hi(t2.x);
        a2 += bf_lo(t0.y) + bf_lo(t2.y);  a3 += bf_hi(t0.y) + bf_hi(t2.y);
        a4 += bf_lo(t0.z) + bf_lo(t2.z);  a5 += bf_hi(t0.z) + bf_hi(t2.z);
        a6 += bf_lo(t0.w) + bf_lo(t2.w);  a7 += bf_hi(t0.w) + bf_hi(t2.w);
        c0 += bf_lo(t1.x) + bf_lo(t3.x);  c1 += bf_hi(t1.x) + bf_hi(t3.x);
        c2 += bf_lo(t1.y) + bf_lo(t3.y);  c3 += bf_hi(t1.y) + bf_hi(t3.y);
        c4 += bf_lo(t1.z) + bf_lo(t3.z);  c5 += bf_hi(t1.z) + bf_hi(t3.z);
        c6 += bf_lo(t1.w) + bf_lo(t3.w);  c7 += bf_hi(t1.w) + bf_hi(t3.w);
        j += 4;
    }
    for (; j < deg; ++j) {
        uint4 t0 = T4[(size_t)ep[j] * 8];
        a0 += bf_lo(t0.x); a1 += bf_hi(t0.x);
        a2 += bf_lo(t0.y); a3 += bf_hi(t0.y);
        a4 += bf_lo(t0.z); a5 += bf_hi(t0.z);
        a6 += bf_lo(t0.w); a7 += bf_hi(t0.w);
    }
    float di = dinv[m];
    if (fq == 0) sDinv[nl] = di;
    int f0 = 8 * fq;
    float av[8] = {a0 + c0, a1 + c1, a2 + c2, a3 + c3,
                   a4 + c4, a5 + c5, a6 + c6, a7 + c7};
    #pragma unroll
    for (int hh = 0; hh < 2; ++hh) {
        float4 hv;
        #pragma unroll
        for (int q = 0; q < 4; ++q) {
            int f = f0 + 4 * hh + q;
            float y = av[4 * hh + q] * di * sSc[f] + sSh[f];
            ((float*)&hv)[q] = (y >= 0.f) ? y : NEG_SLOPE * y;
        }
        *(float4*)&sH[nl][f0 + 4 * hh] = hv;
    }
    __syncthreads();
    int fp = threadIdx.x & 15;                           // feature pair 0..15
    int ng = threadIdx.x >> 4;                           // 0..15
    const float2* w3 = (const float2*)sW3 + fp;          // float2 stride 16 per k
    const float4* sHA = (const float4*)&sH[ng][0];
    const float4* sHB = (const float4*)&sH[ng + 16][0];
    float p0 = 0.f, p1 = 0.f, q0 = 0.f, q1 = 0.f;
    #pragma unroll 4
    for (int k4 = 0; k4 < 16; ++k4) {
        float4 hA = sHA[k4];
        float4 hB = sHB[k4];
        float2 w;
        w = w3[(4 * k4 + 0) * 16];
        p0 = fmaf(hA.x, w.x, p0); p1 = fmaf(hA.x, w.y, p1);
        q0 = fmaf(hB.x, w.x, q0); q1 = fmaf(hB.x, w.y, q1);
        w = w3[(4 * k4 + 1) * 16];
        p0 = fmaf(hA.y, w.x, p0); p1 = fmaf(hA.y, w.y, p1);
        q0 = fmaf(hB.y, w.x, q0); q1 = fmaf(hB.y, w.y, q1);
        w = w3[(4 * k4 + 2) * 16];
        p0 = fmaf(hA.z, w.x, p0); p1 = fmaf(hA.z, w.y, p1);
        q0 = fmaf(hB.z, w.x, q0); q1 = fmaf(hB.z, w.y, q1);
        w = w3[(4 * k4 + 3) * 16];
        p0 = fmaf(hA.w, w.x, p0); p1 = fmaf(hA.w, w.y, p1);
        q0 = fmaf(hB.w, w.x, q0); q1 = fmaf(hB.w, w.y, q1);
    }
    int base = blockIdx.x * 32;
    int nA = base + ng, nB = base + ng + 16;
    if (nA < N) { float d = sDinv[ng];      Tp2[(size_t)nA * 16 + fp] = pack2_bf16(p0 * d, p1 * d); }
    if (nB < N) { float d = sDinv[ng + 16]; Tp2[(size_t)nB * 16 + fp] = pack2_bf16(q0 * d, q1 * d); }
}

// ---- fused layer-3 gather + BN3 + LReLU + mean-pool accumulate.
// R8: same software-pipelined gather as layer2.
#define SLOTS 16
__global__ void __launch_bounds__(256) layer3_gather_pool_kernel(
        const uint32_t* __restrict__ Tp2, const int* __restrict__ rowptr,
        const int* __restrict__ cnt, const int* __restrict__ eidx,
        const float* __restrict__ dinv, const int* __restrict__ batch,
        const float* __restrict__ b3, const float* __restrict__ g3,
        const float* __restrict__ be3, const float* __restrict__ rm3,
        const float* __restrict__ rv3,
        float* __restrict__ out, float* __restrict__ gcnt, int N) {
    __shared__ float sSc[32], sSh[32];
    __shared__ float sAcc[SLOTS][32];
    __shared__ int sCnt[SLOTS];
    if (threadIdx.x < 32) {
        int f = threadIdx.x;
        float sc = rsqrtf(rv3[f] + EPS_BN) * g3[f];
        sSc[f] = sc;
        sSh[f] = (b3[f] - rm3[f]) * sc + be3[f];
    }
    for (int i = threadIdx.x; i < SLOTS * 32; i += 256) ((float*)sAcc)[i] = 0.f;
    if (threadIdx.x < SLOTS) sCnt[threadIdx.x] = 0;
    __syncthreads();
    int fq = threadIdx.x & 3;
    int nl = threadIdx.x >> 2;                           // 0..63
    int node = blockIdx.x * 64 + nl;
    bool valid = node < N;
    int m = valid ? node : N - 1;
    const uint4* T4 = (const uint4*)Tp2 + fq;            // stride 4 uint4 per node
    int start = rowptr[m];
    int deg = cnt[m];
    uint4 ts = T4[(size_t)m * 4];
    float a0 = bf_lo(ts.x), a1 = bf_hi(ts.x), a2 = bf_lo(ts.y), a3 = bf_hi(ts.y);
    float a4 = bf_lo(ts.z), a5 = bf_hi(ts.z), a6 = bf_lo(ts.w), a7 = bf_hi(ts.w);
    float c0 = 0.f, c1 = 0.f, c2 = 0.f, c3 = 0.f;
    float c4 = 0.f, c5 = 0.f, c6 = 0.f, c7 = 0.f;
    const int* ep = eidx + start;
    int j = 0;
    int s0, s1, s2, s3;
    if (deg >= 4) { s0 = ep[0]; s1 = ep[1]; s2 = ep[2]; s3 = ep[3]; }
    for (; j + 8 <= deg; j += 4) {                       // pipelined: prefetch j+4..j+7
        uint4 t0 = T4[(size_t)s0 * 4];
        uint4 t1 = T4[(size_t)s1 * 4];
        uint4 t2 = T4[(size_t)s2 * 4];
        uint4 t3 = T4[(size_t)s3 * 4];
        s0 = ep[j + 4]; s1 = ep[j + 5]; s2 = ep[j + 6]; s3 = ep[j + 7];
        a0 += bf_lo(t0.x) + bf_lo(t2.x);  a1 += bf_hi(t0.x) + bf_hi(t2.x);
        a2 += bf_lo(t0.y) + bf_lo(t2.y);  a3 += bf_hi(t0.y) + bf_hi(t2.y);
        a4 += bf_lo(t0.z) + bf_lo(t2.z);  a5 += bf_hi(t0.z) + bf_hi(t2.z);
        a6 += bf_lo(t0.w) + bf_lo(t2.w);  a7 += bf_hi(t0.w) + bf_hi(t2.w);
        c0 += bf_lo(t1.x) + bf_lo(t3.x);  c1 += bf_hi(t1.x) + bf_hi(t3.x);
        c2 += bf_lo(t1.y) + bf_lo(t3.y);  c3 += bf_hi(t1.y) + bf_hi(t3.y);
        c4 += bf_lo(t1.z) + bf_lo(t3.z);  c5 += bf_hi(t1.z) + bf_hi(t3.z);
        c6 += bf_lo(t1.w) + bf_lo(t3.w);  c7 += bf_hi(t1.w) + bf_hi(t3.w);
    }
    if (j + 4 <= deg) {                                  // drain the prefetched quad
        uint4 t0 = T4[(size_t)s0 * 4];
        uint4 t1 = T4[(size_t)s1 * 4];
        uint4 t2 = T4[(size_t)s2 * 4];
        uint4 t3 = T4[(size_t)s3 * 4];
        a0 += bf_lo(t0.x) + bf_lo(t2.x);  a1 += bf_hi(t0.x) + bf_hi(t2.x);
        a2 += bf_lo(t0.y) + bf_lo(t2.y);  a3 += bf_hi(t0.y) + bf_hi(t2.y);
        a4 += bf_lo(t0.z) + bf_lo(t2.z);  a5 += bf_hi(t0.z) + bf_hi(t2.z);
        a6 += bf_lo(t0.w) + bf_lo(t2.w);  a7 += bf_hi(t0.w) + bf_hi(t2.w);
        c0 += bf_lo(t1.x) + bf_lo(t3.x);  c1 += bf_hi(t1.x) + bf_hi(t3.x);
        c2 += bf_lo(t1.y) + bf_lo(t3.y);  c3 += bf_hi(t1.y) + bf_hi(t3.y);
        c4 += bf_lo(t1.z) + bf_lo(t3.z);  c5 += bf_hi(t1.z) + bf_hi(t3.z);
        c6 += bf_lo(t1.w) + bf_lo(t3.w);  c7 += bf_hi(t1.w) + bf_hi(t3.w);
        j += 4;
    }
    for (; j < deg; ++j) {
        uint4 t0 = T4[(size_t)ep[j] * 4];
        a0 += bf_lo(t0.x); a1 += bf_hi(t0.x);
        a2 += bf_lo(t0.y); a3 += bf_hi(t0.y);
        a4 += bf_lo(t0.z); a5 += bf_hi(t0.z);
        a6 += bf_lo(t0.w); a7 += bf_hi(t0.w);
    }
    float di = dinv[m];
    int f0 = 8 * fq;
    float av[8] = {a0 + c0, a1 + c1, a2 + c2, a3 + c3,
                   a4 + c4, a5 + c5, a6 + c6, a7 + c7};
    float y[8];
    #pragma unroll
    for (int q = 0; q < 8; ++q) {
        float yy = av[q] * di * sSc[f0 + q] + sSh[f0 + q];
        y[q] = (yy >= 0.f) ? yy : NEG_SLOPE * yy;
    }
    int g0 = batch[blockIdx.x * 64];                     // first node of block, always < N
    if (valid) {
        int g = batch[node];
        int slot = g - g0;
        if (slot < SLOTS) {
            #pragma unroll
            for (int q = 0; q < 8; ++q) atomicAdd(&sAcc[slot][f0 + q], y[q]);
            if (fq == 0) atomicAdd(&sCnt[slot], 1);
        } else {                                         // rare: block spans many graphs
            #pragma unroll
            for (int q = 0; q < 8; ++q) atomicAdd(&out[(g << 5) + f0 + q], y[q]);
            if (fq == 0) atomicAdd(&gcnt[g], 1.f);
        }
    }
    __syncthreads();
    for (int i = threadIdx.x; i < SLOTS * 32; i += 256) {
        int s = i >> 5;
        if (sCnt[s] > 0)
            atomicAdd(&out[((g0 + s) << 5) + (i & 31)], ((float*)sAcc)[i]);
    }
    if (threadIdx.x < SLOTS && sCnt[threadIdx.x] > 0)
        atomicAdd(&gcnt[g0 + threadIdx.x], (float)sCnt[threadIdx.x]);
}

__global__ void pool_div_kernel(float* __restrict__ out, const float* __restrict__ gcnt, int G) {
    int tid = blockIdx.x * blockDim.x + threadIdx.x;
    if (tid < (G << 5)) out[tid] /= fmaxf(gcnt[tid >> 5], 1.0f);
}

extern "C" void kernel_launch(void* const* d_in, const int* in_sizes, int n_in,
                              void* d_out, int out_size, void* d_ws, size_t ws_size,
                              hipStream_t stream) {
    const float* x   = (const float*)d_in[0];
    const float* W1  = (const float*)d_in[1];
    const float* b1  = (const float*)d_in[2];
    const float* g1  = (const float*)d_in[3];
    const float* be1 = (const float*)d_in[4];
    const float* rm1 = (const float*)d_in[5];
    const float* rv1 = (const float*)d_in[6];
    const float* W2  = (const float*)d_in[7];
    const float* b2  = (const float*)d_in[8];
    const float* g2  = (const float*)d_in[9];
    const float* be2 = (const float*)d_in[10];
    const float* rm2 = (const float*)d_in[11];
    const float* rv2 = (const float*)d_in[12];
    const float* W3  = (const float*)d_in[13];
    const float* b3  = (const float*)d_in[14];
    const float* g3  = (const float*)d_in[15];
    const float* be3 = (const float*)d_in[16];
    const float* rm3 = (const float*)d_in[17];
    const float* rv3 = (const float*)d_in[18];
    const int* ei    = (const int*)d_in[19];
    const int* batch = (const int*)d_in[20];

    const int N = in_sizes[0] / 3;
    const int E = in_sizes[19] / 2;
    const int G = out_size / 32;
    const int* src = ei;
    const int* dst = ei + E;

    const int B = 256;
    const int nbins = (N + BINSIZE - 1) >> BINSHIFT;                  // 196 for N=100k
    const int cap = (((E / nbins) * 3) / 2 + 15) & ~15;               // 1.5x mean
    const int STAGE_BLOCKS = 512;
    const int chunk = (((E + STAGE_BLOCKS - 1) / STAGE_BLOCKS) + 3) & ~3;  // 4-aligned

    // workspace layout (staged aliases Tp, dead before layer1_gemm2 writes Tp)
    int*      gcur    = (int*)d_ws;                       // 256*GSTRIDE
    int*      cnt     = gcur + 256 * GSTRIDE;             // N
    float*    dinv    = (float*)(cnt + N);                // N
    int*      rowptr  = (int*)(dinv + N);                 // N
    int*      eidx    = rowptr + N;                       // E
    float4*   xs      = (float4*)(((uintptr_t)(eidx + E) + 15) & ~(uintptr_t)15);  // N
    uint32_t* Tp      = (uint32_t*)(xs + N);              // N*32 (layer-2 input, packed bf16)
    uint32_t* Tp2     = Tp + (size_t)N * 32;              // N*16 (layer-3 input, packed bf16)
    float*    gcnt    = (float*)(Tp2 + (size_t)N * 16);   // G
    uint32_t* staged  = Tp;                               // alias: dead before Tp written
    float*    out     = (float*)d_out;

    // ---- CSR build: multisplit stage -> per-bin fill ----
    hipMemsetAsync(gcur, 0, 256 * GSTRIDE * 4, stream);
    stage_ms_kernel<<<STAGE_BLOCKS, 256, 0, stream>>>(src, dst, gcur, staged, cap, nbins, E, chunk);
    fill_csr_kernel<<<nbins, 256, 0, stream>>>(staged, gcur, x, cap, nbins,
                                               rowptr, cnt, dinv, xs, eidx, N, out, gcnt, G);

    // ---- layer 1 + GEMM W2 fused: xs/CSR -> Tp (packed bf16) ----
    layer1_gemm2_kernel<<<(N + 31) / 32, 256, 0, stream>>>(
        xs, rowptr, cnt, eidx, dinv, W1, b1, g1, be1, rm1, rv1, W2, Tp, N);

    // ---- layer 2 gather + GEMM W3 fused: Tp/CSR -> Tp2 (packed bf16) ----
    layer2_gather_gemm3_kernel<<<(N + 31) / 32, 256, 0, stream>>>(
        Tp, rowptr, cnt, eidx, dinv, b2, g2, be2, rm2, rv2, W3, Tp2, N);

    // ---- layer 3 gather + mean-pool fused: Tp2/CSR -> out/gcnt atomics ----
    layer3_gather_pool_kernel<<<(N + 63) / 64, 256, 0, stream>>>(
        Tp2, rowptr, cnt, eidx, dinv, batch, b3, g3, be3, rm3, rv3, out, gcnt, N);

    pool_div_kernel<<<(G * 32 + B - 1) / B, B, 0, stream>>>(out, gcnt, G);
}